// Round 22
// baseline (726.533 us; speedup 1.0000x reference)
//
#include <hip/hip_runtime.h>
#include <hip/hip_bf16.h>
#include <math.h>

#define QMAX 127.0f

// ---- absmax slots (uint-as-float bits) ----
// 0: ln1 y   2: xa(bf16)   3: h(gelu,bf16)   4: ln2 y
// 6: qkv_w   7: proj_w     8: fc1_w          9: fc2_w

typedef unsigned short ushortx8 __attribute__((ext_vector_type(8)));
typedef short bf16x8 __attribute__((ext_vector_type(8)));
typedef float f32x4 __attribute__((ext_vector_type(4)));
typedef int int32x4 __attribute__((ext_vector_type(4)));

__device__ inline float bf2f(unsigned short u) {
    return __uint_as_float(((unsigned int)u) << 16);
}
__device__ inline unsigned short f2bf(float f) {
    __hip_bfloat16 h = __float2bfloat16(f);   // round-to-nearest-even
    return *reinterpret_cast<unsigned short*>(&h);
}

// fast exact-gelu: erf via Abramowitz-Stegun 7.1.26 (|err|<=1.5e-7), branch-free.
__device__ inline float gelu_fast(float v) {
    float z = v * 0.70710678118654752f;
    float a = fabsf(z);
    float t = __builtin_amdgcn_rcpf(fmaf(0.3275911f, a, 1.0f));
    float poly = t * fmaf(t, fmaf(t, fmaf(t, fmaf(t, 1.061405429f, -1.453152027f),
                       1.421413741f), -0.284496736f), 0.254829592f);
    float e = exp2f(-a * a * 1.44269504088896340736f);
    float erfa = 1.0f - poly * e;                 // erf(|z|)
    float erfz = (z < 0.f) ? -erfa : erfa;
    return 0.5f * v * (1.0f + erfz);
}

// async global->LDS DMA: 16B per lane; LDS dest = wave-uniform base + lane*16
__device__ inline void gload16(const char* g, char* l) {
    __builtin_amdgcn_global_load_lds(
        (const __attribute__((address_space(1))) unsigned int*)g,
        (__attribute__((address_space(3))) unsigned int*)l, 16, 0, 0);
}

// bijective XCD-chunked block swizzle (m204)
__device__ inline int xcd_swizzle(int orig, int nwg) {
    int q = nwg >> 3, r = nwg & 7;
    int x = orig & 7, pos = orig >> 3;
    return (x < r ? x * (q + 1) : r * (q + 1) + (x - r) * q) + pos;
}

__global__ void init_slots(unsigned int* am) {
    if (threadIdx.x < 16) am[threadIdx.x] = 0u;
}

// ---------------- absmax over fp32 array ----------------
__global__ __launch_bounds__(256) void absmax_f32(
    const float* __restrict__ p, size_t n, unsigned int* __restrict__ slot)
{
    float lmax = 0.f;
    for (size_t i = (size_t)blockIdx.x*256 + threadIdx.x; i < n; i += (size_t)gridDim.x*256)
        lmax = fmaxf(lmax, fabsf(p[i]));
    __shared__ float rs[256];
    int t = threadIdx.x;
    rs[t] = lmax; __syncthreads();
    for (int o = 128; o; o >>= 1) {
        if (t < o) rs[t] = fmaxf(rs[t], rs[t+o]);
        __syncthreads();
    }
    if (t == 0) atomicMax(slot, __float_as_uint(rs[0]));
}

// ---------------- weight quantize: fp32 -> int8 ----------------
__global__ __launch_bounds__(256) void quant_w(
    const float* __restrict__ w, char* __restrict__ q, size_t n,
    const unsigned int* __restrict__ slot)
{
    float s = __uint_as_float(*slot) / QMAX + 1e-8f;
    for (size_t i = (size_t)blockIdx.x*256 + threadIdx.x; i < n; i += (size_t)gridDim.x*256) {
        float k = fminf(fmaxf(rintf(w[i] / s), -QMAX), QMAX);
        q[i] = (char)(int)k;
    }
}

// ---------------- activation quantize: bf16 -> int8 (8 elems/thread/iter) ----------------
__global__ __launch_bounds__(256) void quant_bf2i8(
    const unsigned short* __restrict__ src, char* __restrict__ dst, size_t n8,
    const unsigned int* __restrict__ slot)
{
    float s  = __uint_as_float(*slot) / QMAX + 1e-8f;
    float rs = 1.0f / s;
    for (size_t i = (size_t)blockIdx.x*256 + threadIdx.x; i < n8; i += (size_t)gridDim.x*256) {
        ushortx8 u = *reinterpret_cast<const ushortx8*>(src + i*8);
        int lo = 0, hi = 0;
        #pragma unroll
        for (int j = 0; j < 4; ++j) {
            int k = (int)fminf(fmaxf(rintf(bf2f(u[j]) * rs), -QMAX), QMAX);
            lo |= (k & 0xff) << (8*j);
        }
        #pragma unroll
        for (int j = 0; j < 4; ++j) {
            int k = (int)fminf(fmaxf(rintf(bf2f(u[4+j]) * rs), -QMAX), QMAX);
            hi |= (k & 0xff) << (8*j);
        }
        reinterpret_cast<int2*>(dst)[i] = make_int2(lo, hi);
    }
}

// ---------------- LayerNorm pass 1: absmax(y), wave-per-row ----------------
__global__ __launch_bounds__(256) void ln_absmax(
    const float* __restrict__ x, const float* __restrict__ g, const float* __restrict__ bia,
    int nrows, unsigned int* __restrict__ slot)
{
    const int lane = threadIdx.x & 63;
    const int wv   = threadIdx.x >> 6;
    int wid = blockIdx.x*4 + wv;
    int nw  = gridDim.x*4;
    const float4* g4 = reinterpret_cast<const float4*>(g);
    const float4* b4 = reinterpret_cast<const float4*>(bia);
    float4 ga = g4[lane], gb = g4[lane+64], gc = g4[lane+128];
    float4 ba = b4[lane], bb = b4[lane+64], bc = b4[lane+128];
    float wmax = 0.f;
    for (int row = wid; row < nrows; row += nw) {
        const float4* xr = reinterpret_cast<const float4*>(x + (size_t)row*768);
        float4 xa = xr[lane], xb = xr[lane+64], xc = xr[lane+128];
        float s  = xa.x+xa.y+xa.z+xa.w + xb.x+xb.y+xb.z+xb.w + xc.x+xc.y+xc.z+xc.w;
        float ss = xa.x*xa.x+xa.y*xa.y+xa.z*xa.z+xa.w*xa.w
                 + xb.x*xb.x+xb.y*xb.y+xb.z*xb.z+xb.w*xb.w
                 + xc.x*xc.x+xc.y*xc.y+xc.z*xc.z+xc.w*xc.w;
        #pragma unroll
        for (int off = 32; off; off >>= 1) {
            s  += __shfl_xor(s,  off);
            ss += __shfl_xor(ss, off);
        }
        float mean = s * (1.0f/768.0f);
        float inv  = rsqrtf(ss * (1.0f/768.0f) - mean*mean + 1e-6f);
        float m = 0.f;
        m = fmaxf(m, fabsf((xa.x-mean)*inv*ga.x + ba.x));
        m = fmaxf(m, fabsf((xa.y-mean)*inv*ga.y + ba.y));
        m = fmaxf(m, fabsf((xa.z-mean)*inv*ga.z + ba.z));
        m = fmaxf(m, fabsf((xa.w-mean)*inv*ga.w + ba.w));
        m = fmaxf(m, fabsf((xb.x-mean)*inv*gb.x + bb.x));
        m = fmaxf(m, fabsf((xb.y-mean)*inv*gb.y + bb.y));
        m = fmaxf(m, fabsf((xb.z-mean)*inv*gb.z + bb.z));
        m = fmaxf(m, fabsf((xb.w-mean)*inv*gb.w + bb.w));
        m = fmaxf(m, fabsf((xc.x-mean)*inv*gc.x + bc.x));
        m = fmaxf(m, fabsf((xc.y-mean)*inv*gc.y + bc.y));
        m = fmaxf(m, fabsf((xc.z-mean)*inv*gc.z + bc.z));
        m = fmaxf(m, fabsf((xc.w-mean)*inv*gc.w + bc.w));
        wmax = fmaxf(wmax, m);
    }
    #pragma unroll
    for (int off = 32; off; off >>= 1)
        wmax = fmaxf(wmax, __shfl_xor(wmax, off));
    __shared__ float red[4];
    if (lane == 0) red[wv] = wmax;
    __syncthreads();
    if (threadIdx.x == 0) {
        float m = fmaxf(fmaxf(red[0], red[1]), fmaxf(red[2], red[3]));
        atomicMax(slot, __float_as_uint(m));
    }
}

// ---------------- LayerNorm pass 2: wave-per-row, emit packed int8 ----------------
__global__ __launch_bounds__(256) void ln_quant(
    const float* __restrict__ x, const float* __restrict__ g, const float* __restrict__ bia,
    int nrows, char* __restrict__ yq, const unsigned int* __restrict__ slot)
{
    const int lane = threadIdx.x & 63;
    const int wv   = threadIdx.x >> 6;
    int wid = blockIdx.x*4 + wv;
    int nw  = gridDim.x*4;
    const float4* g4 = reinterpret_cast<const float4*>(g);
    const float4* b4 = reinterpret_cast<const float4*>(bia);
    float4 ga = g4[lane], gb = g4[lane+64], gc = g4[lane+128];
    float4 ba = b4[lane], bb = b4[lane+64], bc = b4[lane+128];
    float s1 = __uint_as_float(*slot) / QMAX + 1e-8f;
    float r1 = 1.0f / s1;
    for (int row = wid; row < nrows; row += nw) {
        const float4* xr = reinterpret_cast<const float4*>(x + (size_t)row*768);
        float4 xa = xr[lane], xb = xr[lane+64], xc = xr[lane+128];
        float s  = xa.x+xa.y+xa.z+xa.w + xb.x+xb.y+xb.z+xb.w + xc.x+xc.y+xc.z+xc.w;
        float ss = xa.x*xa.x+xa.y*xa.y+xa.z*xa.z+xa.w*xa.w
                 + xb.x*xb.x+xb.y*xb.y+xb.z*xb.z+xb.w*xb.w
                 + xc.x*xc.x+xc.y*xc.y+xc.z*xc.z+xc.w*xc.w;
        #pragma unroll
        for (int off = 32; off; off >>= 1) {
            s  += __shfl_xor(s,  off);
            ss += __shfl_xor(ss, off);
        }
        float mean = s * (1.0f/768.0f);
        float inv  = rsqrtf(ss * (1.0f/768.0f) - mean*mean + 1e-6f);
        int* yr = reinterpret_cast<int*>(yq + (size_t)row*768);
        float y0, y1, y2, y3;
        int p;
        y0 = (xa.x-mean)*inv*ga.x + ba.x; y1 = (xa.y-mean)*inv*ga.y + ba.y;
        y2 = (xa.z-mean)*inv*ga.z + ba.z; y3 = (xa.w-mean)*inv*ga.w + ba.w;
        p  = ((int)fminf(fmaxf(rintf(y0*r1), -QMAX), QMAX) & 0xff)
           | (((int)fminf(fmaxf(rintf(y1*r1), -QMAX), QMAX) & 0xff) << 8)
           | (((int)fminf(fmaxf(rintf(y2*r1), -QMAX), QMAX) & 0xff) << 16)
           | (((int)fminf(fmaxf(rintf(y3*r1), -QMAX), QMAX) & 0xff) << 24);
        yr[lane] = p;
        y0 = (xb.x-mean)*inv*gb.x + bb.x; y1 = (xb.y-mean)*inv*gb.y + bb.y;
        y2 = (xb.z-mean)*inv*gb.z + bb.z; y3 = (xb.w-mean)*inv*gb.w + bb.w;
        p  = ((int)fminf(fmaxf(rintf(y0*r1), -QMAX), QMAX) & 0xff)
           | (((int)fminf(fmaxf(rintf(y1*r1), -QMAX), QMAX) & 0xff) << 8)
           | (((int)fminf(fmaxf(rintf(y2*r1), -QMAX), QMAX) & 0xff) << 16)
           | (((int)fminf(fmaxf(rintf(y3*r1), -QMAX), QMAX) & 0xff) << 24);
        yr[lane+64] = p;
        y0 = (xc.x-mean)*inv*gc.x + bc.x; y1 = (xc.y-mean)*inv*gc.y + bc.y;
        y2 = (xc.z-mean)*inv*gc.z + bc.z; y3 = (xc.w-mean)*inv*gc.w + bc.w;
        p  = ((int)fminf(fmaxf(rintf(y0*r1), -QMAX), QMAX) & 0xff)
           | (((int)fminf(fmaxf(rintf(y1*r1), -QMAX), QMAX) & 0xff) << 8)
           | (((int)fminf(fmaxf(rintf(y2*r1), -QMAX), QMAX) & 0xff) << 16)
           | (((int)fminf(fmaxf(rintf(y3*r1), -QMAX), QMAX) & 0xff) << 24);
        yr[lane+128] = p;
    }
}

// ---------------- int8 MFMA GEMM: R18 ring-3 + validated chunk swizzle ----------------
// Only change vs R18: both-sides chunk swizzle (R19-validated math) to kill the
// 8-way ds_read bank conflict. Pre-swizzled GLOBAL source (gload dest stays
// linear, rule 21) + matching involution on the fragment read:
//   stage  src chunk = (lane&3) ^ ((lane>>3)&3)     [= chunk ^ ((row>>1)&3)]
//   read  phys chunk = lk ^ ((lr>>1)&3)
// Lanes 0..15 then hit 8 distinct banks x 2 lanes = free 2-way (was 2 banks/8-way).
__global__ __launch_bounds__(256) void gemm_i8(
    const char* __restrict__ Alo, const char* __restrict__ Ahi, int split_row,
    const char* __restrict__ Wq,
    const float* __restrict__ bias, const float* __restrict__ residual,
    void* __restrict__ outp, int M, int N, int K,
    const unsigned int* __restrict__ slotA, float epsA,
    const unsigned int* __restrict__ slotW,
    int apply_gelu, int out_bf16, unsigned int* __restrict__ am_slot)
{
    __shared__ __align__(16) char As0[128*64];
    __shared__ __align__(16) char Ws0[128*64];
    __shared__ __align__(16) char As1[128*64];
    __shared__ __align__(16) char Ws1[128*64];
    __shared__ __align__(16) char As2[128*64];
    __shared__ __align__(16) char Ws2[128*64];
    __shared__ float sred[256];

    float sA  = __uint_as_float(*slotA) / QMAX + epsA;
    float sW  = __uint_as_float(*slotW) / QMAX + 1e-8f;

    const int t    = threadIdx.x;
    const int lane = t & 63;
    const int w    = t >> 6;
    const int wr   = w >> 1;
    const int wc   = w & 1;
    const int lr   = lane & 15;
    const int lk   = lane >> 4;

    const int gx   = gridDim.x;
    const int nwg  = gx * gridDim.y;
    const int wg   = xcd_swizzle(blockIdx.y * gx + blockIdx.x, nwg);
    const int n0   = (wg % gx) * 128;
    const int m0   = (wg / gx) * 128;

    const int rsub = lane >> 2;                          // row within call 0..15
    const int csub = ((lane & 3) ^ ((lane >> 3) & 3)) * 16;  // pre-swizzled src chunk
    const int rchk = (lk ^ ((lr >> 1) & 3)) * 16;        // swizzled read chunk

    int32x4 acc[4][4];
    #pragma unroll
    for (int i = 0; i < 4; ++i)
        #pragma unroll
        for (int j = 0; j < 4; ++j)
            acc[i][j] = (int32x4){0,0,0,0};

    auto STAGE = [&](char* Ab, char* Wb, int kt) {   // exactly 4 VMEM ops per wave
        #pragma unroll
        for (int c = 0; c < 2; ++c) {
            int row  = w*32 + c*16 + rsub;
            int grow = m0 + row;
            if (grow > M-1) grow = M-1;      // clamp (junk only feeds m>=M, skipped)
            const char* base = (grow < split_row) ? Alo : Ahi;
            gload16(base + (size_t)grow*K + kt + csub, Ab + (size_t)(w*32 + c*16)*64);
        }
        #pragma unroll
        for (int c = 0; c < 2; ++c) {
            int row = w*32 + c*16 + rsub;
            gload16(Wq + (size_t)(n0 + row)*K + kt + csub, Wb + (size_t)(w*32 + c*16)*64);
        }
    };
    auto COMPUTE = [&](const char* Ab, const char* Wb) {
        int32x4 af[4], bw[4];
        #pragma unroll
        for (int mi = 0; mi < 4; ++mi)
            af[mi] = *reinterpret_cast<const int32x4*>(
                &Ab[(wr*64 + mi*16 + lr)*64 + rchk]);
        #pragma unroll
        for (int ni = 0; ni < 4; ++ni)
            bw[ni] = *reinterpret_cast<const int32x4*>(
                &Wb[(wc*64 + ni*16 + lr)*64 + rchk]);
        #pragma unroll
        for (int mi = 0; mi < 4; ++mi)
            #pragma unroll
            for (int ni = 0; ni < 4; ++ni)
                acc[mi][ni] = __builtin_amdgcn_mfma_i32_16x16x64_i8(
                    af[mi], bw[ni], acc[mi][ni], 0, 0, 0);
    };

    const int nk = K >> 6;   // 12 or 48: divisible by 3
    STAGE(As0, Ws0, 0);
    STAGE(As1, Ws1, 1 << 6);
    int kt = 0;
    for (; kt + 3 < nk; kt += 3) {
        asm volatile("s_waitcnt vmcnt(4)" ::: "memory");   // buf0 landed (buf1 in flight)
        __builtin_amdgcn_sched_barrier(0);
        __builtin_amdgcn_s_barrier();
        STAGE(As2, Ws2, (kt+2) << 6);
        COMPUTE(As0, Ws0);
        asm volatile("s_waitcnt vmcnt(4)" ::: "memory");   // buf1 landed
        __builtin_amdgcn_sched_barrier(0);
        __builtin_amdgcn_s_barrier();
        STAGE(As0, Ws0, (kt+3) << 6);
        COMPUTE(As1, Ws1);
        asm volatile("s_waitcnt vmcnt(4)" ::: "memory");   // buf2 landed
        __builtin_amdgcn_sched_barrier(0);
        __builtin_amdgcn_s_barrier();
        STAGE(As1, Ws1, (kt+4) << 6);
        COMPUTE(As2, Ws2);
    }
    // final triple (kt == nk-3)
    asm volatile("s_waitcnt vmcnt(4)" ::: "memory");
    __builtin_amdgcn_sched_barrier(0);
    __builtin_amdgcn_s_barrier();
    STAGE(As2, Ws2, (kt+2) << 6);
    COMPUTE(As0, Ws0);
    asm volatile("s_waitcnt vmcnt(4)" ::: "memory");       // buf1 landed, buf2 in flight
    __builtin_amdgcn_sched_barrier(0);
    __builtin_amdgcn_s_barrier();
    COMPUTE(As1, Ws1);
    asm volatile("s_waitcnt vmcnt(0)" ::: "memory");       // drain buf2
    __builtin_amdgcn_sched_barrier(0);
    __builtin_amdgcn_s_barrier();
    COMPUTE(As2, Ws2);

    // ---- epilogue: C/D map col=lane&15, row=(lane>>4)*4+reg ----
    float scale = sA * sW;
    float lmax = 0.f;
    #pragma unroll
    for (int mi = 0; mi < 4; ++mi) {
        #pragma unroll
        for (int j = 0; j < 4; ++j) {
            int m = m0 + wr*64 + mi*16 + lk*4 + j;
            if (m >= M) continue;
            #pragma unroll
            for (int ni = 0; ni < 4; ++ni) {
                int n = n0 + wc*64 + ni*16 + lr;
                float v = scale * (float)acc[mi][ni][j] + bias[n];
                if (residual) v += residual[(size_t)m*N + n];
                if (apply_gelu) v = gelu_fast(v);
                if (out_bf16) {
                    unsigned short ub = f2bf(v);
                    ((unsigned short*)outp)[(size_t)m*N + n] = ub;
                    lmax = fmaxf(lmax, fabsf(bf2f(ub)));
                } else {
                    ((float*)outp)[(size_t)m*N + n] = v;
                    lmax = fmaxf(lmax, fabsf(v));
                }
            }
        }
    }
    if (am_slot) {
        sred[t] = lmax; __syncthreads();
        for (int o = 128; o; o >>= 1) {
            if (t < o) sred[t] = fmaxf(sred[t], sred[t+o]);
            __syncthreads();
        }
        if (t == 0) atomicMax(am_slot, __float_as_uint(sred[0]));
    }
}

// ---------------- MFMA flash attention: swapped QK^T (unchanged from R15) ----------------
__global__ __launch_bounds__(512) void attn_mfma(
    const unsigned short* __restrict__ qkv, unsigned short* __restrict__ xa,
    unsigned int* __restrict__ am_slot)
{
    const int Nn = 577;
    const float SCL2 = 0.125f * 1.44269504088896340736f;
    const int gx = gridDim.x;
    const int wg = xcd_swizzle(blockIdx.y * gx + blockIdx.x, gx * gridDim.y);
    const int q0 = (wg % gx) * 128;
    const int bh = wg / gx;
    const int h  = bh % 12;
    const int b  = bh / 12;
    const int t  = threadIdx.x;
    const int w    = t >> 6;
    const int lane = t & 63;
    const int lr   = lane & 15;
    const int lk   = lane >> 4;

    __shared__ __align__(16) unsigned short Ks[64][72];
    __shared__ __align__(16) unsigned short Vt[64][72];
    __shared__ __align__(16) unsigned short Pw[8][16][72];
    __shared__ float red8[8];

    const size_t rowstride = 2304;
    const size_t basebh = ((size_t)b * Nn) * rowstride + (size_t)h * 64;

    bf16x8 qf[2];
    {
        int row = q0 + w*16 + lr;
        if (row < Nn) {
            const unsigned short* qrow = qkv + (size_t)row * rowstride + basebh;
            qf[0] = *reinterpret_cast<const bf16x8*>(qrow + lk*8);
            qf[1] = *reinterpret_cast<const bf16x8*>(qrow + 32 + lk*8);
        } else {
            #pragma unroll
            for (int j = 0; j < 8; ++j) { qf[0][j] = 0; qf[1][j] = 0; }
        }
    }

    float m_run = -INFINITY, l_run = 0.f;
    f32x4 acc_o[4];
    #pragma unroll
    for (int df = 0; df < 4; ++df) acc_o[df] = (f32x4){0.f,0.f,0.f,0.f};

    for (int kt = 0; kt < 10; ++kt) {
        __syncthreads();
        {
            int r   = t >> 3;
            int e8  = (t & 7) * 8;
            int key = kt*64 + r;
            ushortx8 ku, vu;
            if (key < Nn) {
                const unsigned short* krow = qkv + (size_t)key * rowstride + basebh;
                ku = *reinterpret_cast<const ushortx8*>(krow + 768  + e8);
                vu = *reinterpret_cast<const ushortx8*>(krow + 1536 + e8);
            } else {
                #pragma unroll
                for (int j = 0; j < 8; ++j) { ku[j] = 0; vu[j] = 0; }
            }
            *reinterpret_cast<ushortx8*>(&Ks[r][e8]) = ku;
            int colp = ((((r >> 3) ^ (t & 7)) << 3) | (r & 7));
            #pragma unroll
            for (int j = 0; j < 8; ++j) Vt[e8 + j][colp] = vu[j];
        }
        __syncthreads();

        f32x4 st[4];
        #pragma unroll
        for (int kf = 0; kf < 4; ++kf) st[kf] = (f32x4){0.f,0.f,0.f,0.f};
        __builtin_amdgcn_s_setprio(1);
        #pragma unroll
        for (int kk = 0; kk < 2; ++kk) {
            #pragma unroll
            for (int kf = 0; kf < 4; ++kf) {
                bf16x8 kfrag = *reinterpret_cast<const bf16x8*>(
                    &Ks[kf*16 + lr][kk*32 + lk*8]);
                st[kf] = __builtin_amdgcn_mfma_f32_16x16x32_bf16(
                    kfrag, qf[kk], st[kf], 0, 0, 0);
            }
        }
        __builtin_amdgcn_s_setprio(0);
        #pragma unroll
        for (int kf = 0; kf < 4; ++kf)
            #pragma unroll
            for (int j = 0; j < 4; ++j) {
                int key = kt*64 + kf*16 + lk*4 + j;
                st[kf][j] = (key < Nn) ? st[kf][j] * SCL2 : -INFINITY;
            }

        float tm = st[0][0];
        #pragma unroll
        for (int kf = 0; kf < 4; ++kf)
            #pragma unroll
            for (int j = 0; j < 4; ++j)
                tm = fmaxf(tm, st[kf][j]);
        tm = fmaxf(tm, __shfl_xor(tm, 16));
        tm = fmaxf(tm, __shfl_xor(tm, 32));

        if (__any(tm > m_run + 8.0f)) {
            float nm  = fmaxf(m_run, tm);
            float fac = exp2f(m_run - nm);
            m_run = nm;
            l_run *= fac;
            float facR[4];
            #pragma unroll
            for (int j = 0; j < 4; ++j)
                facR[j] = __shfl(fac, lk*4 + j);
            #pragma unroll
            for (int df = 0; df < 4; ++df)
                #pragma unroll
                for (int j = 0; j < 4; ++j)
                    acc_o[df][j] *= facR[j];
        }

        float ps = 0.f;
        #pragma unroll
        for (int kf = 0; kf < 4; ++kf)
            #pragma unroll
            for (int j = 0; j < 4; ++j) {
                float p = exp2f(st[kf][j] - m_run);
                st[kf][j] = p;
                ps += p;
            }
        ps += __shfl_xor(ps, 16);
        ps += __shfl_xor(ps, 32);
        l_run += ps;

        #pragma unroll
        for (int kf = 0; kf < 4; ++kf)
            #pragma unroll
            for (int j = 0; j < 4; ++j)
                Pw[w][lr][kf*16 + lk*4 + j] = f2bf(st[kf][j]);

        __builtin_amdgcn_s_setprio(1);
        #pragma unroll
        for (int kk = 0; kk < 2; ++kk) {
            bf16x8 pf = *reinterpret_cast<const bf16x8*>(
                &Pw[w][lr][kk*32 + lk*8]);
            #pragma unroll
            for (int df = 0; df < 4; ++df) {
                int ar = df*2 + (lr >> 3);
                bf16x8 vf = *reinterpret_cast<const bf16x8*>(
                    &Vt[df*16 + lr][(((kk*4 + lk) ^ ar) << 3)]);
                acc_o[df] = __builtin_amdgcn_mfma_f32_16x16x32_bf16(
                    pf, vf, acc_o[df], 0, 0, 0);
            }
        }
        __builtin_amdgcn_s_setprio(0);
    }

    float lrow[4];
    #pragma unroll
    for (int j = 0; j < 4; ++j)
        lrow[j] = __shfl(l_run, lk*4 + j);
    float lmax = 0.f;
    #pragma unroll
    for (int j = 0; j < 4; ++j) {
        int m = q0 + w*16 + lk*4 + j;
        if (m < Nn) {
            float rl = 1.0f / lrow[j];
            #pragma unroll
            for (int df = 0; df < 4; ++df) {
                int d = df*16 + lr;
                float o = acc_o[df][j] * rl;
                unsigned short ob = f2bf(o);
                xa[((size_t)(b*Nn + m))*768 + h*64 + d] = ob;
                lmax = fmaxf(lmax, fabsf(bf2f(ob)));
            }
        }
    }
    #pragma unroll
    for (int off = 1; off < 64; off <<= 1)
        lmax = fmaxf(lmax, __shfl_xor(lmax, off));
    if (lane == 0) red8[w] = lmax;
    __syncthreads();
    if (t == 0) {
        float m = 0.f;
        #pragma unroll
        for (int i = 0; i < 8; ++i) m = fmaxf(m, red8[i]);
        atomicMax(am_slot, __float_as_uint(m));
    }
}

extern "C" void kernel_launch(void* const* d_in, const int* in_sizes, int n_in,
                              void* d_out, int out_size, void* d_ws, size_t ws_size,
                              hipStream_t stream)
{
    const float* x      = (const float*)d_in[0];
    const float* ln1_g  = (const float*)d_in[1];
    const float* ln1_b  = (const float*)d_in[2];
    const float* qkv_w  = (const float*)d_in[3];
    const float* qkv_b  = (const float*)d_in[4];
    const float* proj_w = (const float*)d_in[5];
    const float* proj_b = (const float*)d_in[6];
    const float* ln2_g  = (const float*)d_in[7];
    const float* ln2_b  = (const float*)d_in[8];
    const float* fc1_w  = (const float*)d_in[9];
    const float* fc1_b  = (const float*)d_in[10];
    const float* fc2_w  = (const float*)d_in[11];
    const float* fc2_b  = (const float*)d_in[12];
    float* out = (float*)d_out;

    const int B = 32, Nn = 577, C = 768, H3 = 3072;
    const int M = B * Nn;                    // 18464
    const size_t nA = (size_t)M * C;         // 14,180,352
    const size_t nQ = (size_t)M * 3 * C;
    const size_t nH = (size_t)M * H3;        // 56,721,408

    const size_t NEEDED = 256 + 2359296 + nA + 2*nH;
    if (ws_size < NEEDED) return;

    char* wsb = (char*)d_ws;
    unsigned int* am = (unsigned int*)wsb;
    char* WQ  = wsb + 256;
    char* XNQ = WQ + 2359296;                 // int8 slot (ln out / xaq / hq-side)
    char* BIG = XNQ + nA;
    unsigned short* QKV = (unsigned short*)BIG;
    unsigned short* XA  = (unsigned short*)(BIG + 2*nQ);
    unsigned short* Hbf = (unsigned short*)BIG;
    char* HQ = BIG;                           // in-place int8 h (rows >= SPLIT)

    const int SPLIT = 4608;
    const size_t rowsB = 9216 - 4608, rowsC = 18432 - 9216, rowsD = 18464 - 18432;

    dim3 blk(256);
    int mt128 = (M + 127) / 128;

    init_slots<<<dim3(1), dim3(16), 0, stream>>>(am);

    // ---- attention branch ----
    ln_absmax<<<dim3(2048), blk, 0, stream>>>(x, ln1_g, ln1_b, M, am + 0);
    ln_quant <<<dim3(2048), blk, 0, stream>>>(x, ln1_g, ln1_b, M, XNQ, am + 0);

    absmax_f32<<<dim3(1024), blk, 0, stream>>>(qkv_w, (size_t)3*C*C, am + 6);
    quant_w  <<<dim3(1024), blk, 0, stream>>>(qkv_w, WQ, (size_t)3*C*C, am + 6);
    gemm_i8<<<dim3(3*C/128, mt128), blk, 0, stream>>>(
        XNQ, XNQ, 0, WQ, qkv_b, nullptr, QKV, M, 3*C, C,
        am + 0, 2e-8f, am + 6, 0, 1, nullptr);

    attn_mfma<<<dim3(5, 384), dim3(512), 0, stream>>>(QKV, XA, am + 2);

    quant_bf2i8<<<dim3(2048), blk, 0, stream>>>(XA, XNQ, nA/8, am + 2);

    absmax_f32<<<dim3(1024), blk, 0, stream>>>(proj_w, (size_t)C*C, am + 7);
    quant_w  <<<dim3(1024), blk, 0, stream>>>(proj_w, WQ, (size_t)C*C, am + 7);
    gemm_i8<<<dim3(C/128, mt128), blk, 0, stream>>>(
        XNQ, XNQ, 0, WQ, proj_b, x, out, M, C, C,
        am + 2, 1e-8f, am + 7, 0, 0, nullptr);          // out = x + proj

    // ---- mlp branch ----
    ln_absmax<<<dim3(2048), blk, 0, stream>>>(out, ln2_g, ln2_b, M, am + 4);
    ln_quant <<<dim3(2048), blk, 0, stream>>>(out, ln2_g, ln2_b, M, XNQ, am + 4);

    absmax_f32<<<dim3(1024), blk, 0, stream>>>(fc1_w, (size_t)H3*C, am + 8);
    quant_w  <<<dim3(1024), blk, 0, stream>>>(fc1_w, WQ, (size_t)H3*C, am + 8);
    gemm_i8<<<dim3(H3/128, mt128), blk, 0, stream>>>(
        XNQ, XNQ, 0, WQ, fc1_b, nullptr, Hbf, M, H3, C,
        am + 4, 2e-8f, am + 8, 1, 1, am + 3);           // gelu, bf16 h, absmax(h)

    quant_bf2i8<<<dim3(2048), blk, 0, stream>>>(
        Hbf, XNQ, (size_t)SPLIT*H3/8, am + 3);
    quant_bf2i8<<<dim3(2048), blk, 0, stream>>>(
        Hbf + (size_t)4608*H3, HQ + (size_t)4608*H3, rowsB*H3/8, am + 3);
    quant_bf2i8<<<dim3(2048), blk, 0, stream>>>(
        Hbf + (size_t)9216*H3, HQ + (size_t)9216*H3, rowsC*H3/8, am + 3);
    quant_bf2i8<<<dim3(48),  blk, 0, stream>>>(
        Hbf + (size_t)18432*H3, HQ + (size_t)18432*H3, rowsD*H3/8, am + 3);

    absmax_f32<<<dim3(1024), blk, 0, stream>>>(fc2_w, (size_t)C*H3, am + 9);
    quant_w  <<<dim3(1024), blk, 0, stream>>>(fc2_w, WQ, (size_t)C*H3, am + 9);
    gemm_i8<<<dim3(C/128, mt128), blk, 0, stream>>>(
        XNQ, HQ, SPLIT, WQ, fc2_b, out, out, M, C, H3,
        am + 3, 1e-8f, am + 9, 0, 0, nullptr);          // out += fc2
}

// Round 23
// 692.879 us; speedup vs baseline: 1.0486x; 1.0486x over previous
//
#include <hip/hip_runtime.h>
#include <hip/hip_bf16.h>
#include <math.h>

#define QMAX 127.0f

// ---- absmax slots (uint-as-float bits) ----
// 0: ln1 y   2: xa(bf16)   3: h(gelu,bf16)   4: ln2 y
// 6: qkv_w   7: proj_w     8: fc1_w          9: fc2_w

typedef unsigned short ushortx8 __attribute__((ext_vector_type(8)));
typedef short bf16x8 __attribute__((ext_vector_type(8)));
typedef float f32x4 __attribute__((ext_vector_type(4)));
typedef int int32x4 __attribute__((ext_vector_type(4)));

__device__ inline float bf2f(unsigned short u) {
    return __uint_as_float(((unsigned int)u) << 16);
}
__device__ inline unsigned short f2bf(float f) {
    __hip_bfloat16 h = __float2bfloat16(f);   // round-to-nearest-even
    return *reinterpret_cast<unsigned short*>(&h);
}

// fast exact-gelu: erf via Abramowitz-Stegun 7.1.26 (|err|<=1.5e-7), branch-free.
__device__ inline float gelu_fast(float v) {
    float z = v * 0.70710678118654752f;
    float a = fabsf(z);
    float t = __builtin_amdgcn_rcpf(fmaf(0.3275911f, a, 1.0f));
    float poly = t * fmaf(t, fmaf(t, fmaf(t, fmaf(t, 1.061405429f, -1.453152027f),
                       1.421413741f), -0.284496736f), 0.254829592f);
    float e = exp2f(-a * a * 1.44269504088896340736f);
    float erfa = 1.0f - poly * e;                 // erf(|z|)
    float erfz = (z < 0.f) ? -erfa : erfa;
    return 0.5f * v * (1.0f + erfz);
}

// async global->LDS DMA: 16B per lane; LDS dest = wave-uniform base + lane*16
__device__ inline void gload16(const char* g, char* l) {
    __builtin_amdgcn_global_load_lds(
        (const __attribute__((address_space(1))) unsigned int*)g,
        (__attribute__((address_space(3))) unsigned int*)l, 16, 0, 0);
}

// bijective XCD-chunked block swizzle (m204)
__device__ inline int xcd_swizzle(int orig, int nwg) {
    int q = nwg >> 3, r = nwg & 7;
    int x = orig & 7, pos = orig >> 3;
    return (x < r ? x * (q + 1) : r * (q + 1) + (x - r) * q) + pos;
}

__global__ void init_slots(unsigned int* am) {
    if (threadIdx.x < 16) am[threadIdx.x] = 0u;
}

// ---------------- merged absmax over 4 fp32 arrays (weights; all independent) ----------------
// blockIdx.y selects the array; writes slots[blockIdx.y] (slots 6..9 contiguous).
__global__ __launch_bounds__(256) void absmax4_f32(
    const float* __restrict__ p0, size_t n0, const float* __restrict__ p1, size_t n1,
    const float* __restrict__ p2, size_t n2, const float* __restrict__ p3, size_t n3,
    unsigned int* __restrict__ slots)
{
    const float* p; size_t n;
    switch (blockIdx.y) {
        case 0:  p = p0; n = n0; break;
        case 1:  p = p1; n = n1; break;
        case 2:  p = p2; n = n2; break;
        default: p = p3; n = n3; break;
    }
    float lmax = 0.f;
    for (size_t i = (size_t)blockIdx.x*256 + threadIdx.x; i < n; i += (size_t)gridDim.x*256)
        lmax = fmaxf(lmax, fabsf(p[i]));
    __shared__ float rs[256];
    int t = threadIdx.x;
    rs[t] = lmax; __syncthreads();
    for (int o = 128; o; o >>= 1) {
        if (t < o) rs[t] = fmaxf(rs[t], rs[t+o]);
        __syncthreads();
    }
    if (t == 0) atomicMax(slots + blockIdx.y, __float_as_uint(rs[0]));
}

// ---------------- weight quantize: fp32 -> int8 ----------------
__global__ __launch_bounds__(256) void quant_w(
    const float* __restrict__ w, char* __restrict__ q, size_t n,
    const unsigned int* __restrict__ slot)
{
    float s = __uint_as_float(*slot) / QMAX + 1e-8f;
    for (size_t i = (size_t)blockIdx.x*256 + threadIdx.x; i < n; i += (size_t)gridDim.x*256) {
        float k = fminf(fmaxf(rintf(w[i] / s), -QMAX), QMAX);
        q[i] = (char)(int)k;
    }
}

// ---------------- activation quantize: bf16 -> int8 (8 elems/thread/iter) ----------------
__global__ __launch_bounds__(256) void quant_bf2i8(
    const unsigned short* __restrict__ src, char* __restrict__ dst, size_t n8,
    const unsigned int* __restrict__ slot)
{
    float s  = __uint_as_float(*slot) / QMAX + 1e-8f;
    float rs = 1.0f / s;
    for (size_t i = (size_t)blockIdx.x*256 + threadIdx.x; i < n8; i += (size_t)gridDim.x*256) {
        ushortx8 u = *reinterpret_cast<const ushortx8*>(src + i*8);
        int lo = 0, hi = 0;
        #pragma unroll
        for (int j = 0; j < 4; ++j) {
            int k = (int)fminf(fmaxf(rintf(bf2f(u[j]) * rs), -QMAX), QMAX);
            lo |= (k & 0xff) << (8*j);
        }
        #pragma unroll
        for (int j = 0; j < 4; ++j) {
            int k = (int)fminf(fmaxf(rintf(bf2f(u[4+j]) * rs), -QMAX), QMAX);
            hi |= (k & 0xff) << (8*j);
        }
        reinterpret_cast<int2*>(dst)[i] = make_int2(lo, hi);
    }
}

// ---------------- LayerNorm pass 1: absmax(y), wave-per-row ----------------
__global__ __launch_bounds__(256) void ln_absmax(
    const float* __restrict__ x, const float* __restrict__ g, const float* __restrict__ bia,
    int nrows, unsigned int* __restrict__ slot)
{
    const int lane = threadIdx.x & 63;
    const int wv   = threadIdx.x >> 6;
    int wid = blockIdx.x*4 + wv;
    int nw  = gridDim.x*4;
    const float4* g4 = reinterpret_cast<const float4*>(g);
    const float4* b4 = reinterpret_cast<const float4*>(bia);
    float4 ga = g4[lane], gb = g4[lane+64], gc = g4[lane+128];
    float4 ba = b4[lane], bb = b4[lane+64], bc = b4[lane+128];
    float wmax = 0.f;
    for (int row = wid; row < nrows; row += nw) {
        const float4* xr = reinterpret_cast<const float4*>(x + (size_t)row*768);
        float4 xa = xr[lane], xb = xr[lane+64], xc = xr[lane+128];
        float s  = xa.x+xa.y+xa.z+xa.w + xb.x+xb.y+xb.z+xb.w + xc.x+xc.y+xc.z+xc.w;
        float ss = xa.x*xa.x+xa.y*xa.y+xa.z*xa.z+xa.w*xa.w
                 + xb.x*xb.x+xb.y*xb.y+xb.z*xb.z+xb.w*xb.w
                 + xc.x*xc.x+xc.y*xc.y+xc.z*xc.z+xc.w*xc.w;
        #pragma unroll
        for (int off = 32; off; off >>= 1) {
            s  += __shfl_xor(s,  off);
            ss += __shfl_xor(ss, off);
        }
        float mean = s * (1.0f/768.0f);
        float inv  = rsqrtf(ss * (1.0f/768.0f) - mean*mean + 1e-6f);
        float m = 0.f;
        m = fmaxf(m, fabsf((xa.x-mean)*inv*ga.x + ba.x));
        m = fmaxf(m, fabsf((xa.y-mean)*inv*ga.y + ba.y));
        m = fmaxf(m, fabsf((xa.z-mean)*inv*ga.z + ba.z));
        m = fmaxf(m, fabsf((xa.w-mean)*inv*ga.w + ba.w));
        m = fmaxf(m, fabsf((xb.x-mean)*inv*gb.x + bb.x));
        m = fmaxf(m, fabsf((xb.y-mean)*inv*gb.y + bb.y));
        m = fmaxf(m, fabsf((xb.z-mean)*inv*gb.z + bb.z));
        m = fmaxf(m, fabsf((xb.w-mean)*inv*gb.w + bb.w));
        m = fmaxf(m, fabsf((xc.x-mean)*inv*gc.x + bc.x));
        m = fmaxf(m, fabsf((xc.y-mean)*inv*gc.y + bc.y));
        m = fmaxf(m, fabsf((xc.z-mean)*inv*gc.z + bc.z));
        m = fmaxf(m, fabsf((xc.w-mean)*inv*gc.w + bc.w));
        wmax = fmaxf(wmax, m);
    }
    #pragma unroll
    for (int off = 32; off; off >>= 1)
        wmax = fmaxf(wmax, __shfl_xor(wmax, off));
    __shared__ float red[4];
    if (lane == 0) red[wv] = wmax;
    __syncthreads();
    if (threadIdx.x == 0) {
        float m = fmaxf(fmaxf(red[0], red[1]), fmaxf(red[2], red[3]));
        atomicMax(slot, __float_as_uint(m));
    }
}

// ---------------- LayerNorm pass 2: wave-per-row, emit packed int8 ----------------
__global__ __launch_bounds__(256) void ln_quant(
    const float* __restrict__ x, const float* __restrict__ g, const float* __restrict__ bia,
    int nrows, char* __restrict__ yq, const unsigned int* __restrict__ slot)
{
    const int lane = threadIdx.x & 63;
    const int wv   = threadIdx.x >> 6;
    int wid = blockIdx.x*4 + wv;
    int nw  = gridDim.x*4;
    const float4* g4 = reinterpret_cast<const float4*>(g);
    const float4* b4 = reinterpret_cast<const float4*>(bia);
    float4 ga = g4[lane], gb = g4[lane+64], gc = g4[lane+128];
    float4 ba = b4[lane], bb = b4[lane+64], bc = b4[lane+128];
    float s1 = __uint_as_float(*slot) / QMAX + 1e-8f;
    float r1 = 1.0f / s1;
    for (int row = wid; row < nrows; row += nw) {
        const float4* xr = reinterpret_cast<const float4*>(x + (size_t)row*768);
        float4 xa = xr[lane], xb = xr[lane+64], xc = xr[lane+128];
        float s  = xa.x+xa.y+xa.z+xa.w + xb.x+xb.y+xb.z+xb.w + xc.x+xc.y+xc.z+xc.w;
        float ss = xa.x*xa.x+xa.y*xa.y+xa.z*xa.z+xa.w*xa.w
                 + xb.x*xb.x+xb.y*xb.y+xb.z*xb.z+xb.w*xb.w
                 + xc.x*xc.x+xc.y*xc.y+xc.z*xc.z+xc.w*xc.w;
        #pragma unroll
        for (int off = 32; off; off >>= 1) {
            s  += __shfl_xor(s,  off);
            ss += __shfl_xor(ss, off);
        }
        float mean = s * (1.0f/768.0f);
        float inv  = rsqrtf(ss * (1.0f/768.0f) - mean*mean + 1e-6f);
        int* yr = reinterpret_cast<int*>(yq + (size_t)row*768);
        float y0, y1, y2, y3;
        int p;
        y0 = (xa.x-mean)*inv*ga.x + ba.x; y1 = (xa.y-mean)*inv*ga.y + ba.y;
        y2 = (xa.z-mean)*inv*ga.z + ba.z; y3 = (xa.w-mean)*inv*ga.w + ba.w;
        p  = ((int)fminf(fmaxf(rintf(y0*r1), -QMAX), QMAX) & 0xff)
           | (((int)fminf(fmaxf(rintf(y1*r1), -QMAX), QMAX) & 0xff) << 8)
           | (((int)fminf(fmaxf(rintf(y2*r1), -QMAX), QMAX) & 0xff) << 16)
           | (((int)fminf(fmaxf(rintf(y3*r1), -QMAX), QMAX) & 0xff) << 24);
        yr[lane] = p;
        y0 = (xb.x-mean)*inv*gb.x + bb.x; y1 = (xb.y-mean)*inv*gb.y + bb.y;
        y2 = (xb.z-mean)*inv*gb.z + bb.z; y3 = (xb.w-mean)*inv*gb.w + bb.w;
        p  = ((int)fminf(fmaxf(rintf(y0*r1), -QMAX), QMAX) & 0xff)
           | (((int)fminf(fmaxf(rintf(y1*r1), -QMAX), QMAX) & 0xff) << 8)
           | (((int)fminf(fmaxf(rintf(y2*r1), -QMAX), QMAX) & 0xff) << 16)
           | (((int)fminf(fmaxf(rintf(y3*r1), -QMAX), QMAX) & 0xff) << 24);
        yr[lane+64] = p;
        y0 = (xc.x-mean)*inv*gc.x + bc.x; y1 = (xc.y-mean)*inv*gc.y + bc.y;
        y2 = (xc.z-mean)*inv*gc.z + bc.z; y3 = (xc.w-mean)*inv*gc.w + bc.w;
        p  = ((int)fminf(fmaxf(rintf(y0*r1), -QMAX), QMAX) & 0xff)
           | (((int)fminf(fmaxf(rintf(y1*r1), -QMAX), QMAX) & 0xff) << 8)
           | (((int)fminf(fmaxf(rintf(y2*r1), -QMAX), QMAX) & 0xff) << 16)
           | (((int)fminf(fmaxf(rintf(y3*r1), -QMAX), QMAX) & 0xff) << 24);
        yr[lane+128] = p;
    }
}

// ---------------- int8 MFMA GEMM: R18 ring-3 + zero-conflict chunk swizzle ----------------
__global__ __launch_bounds__(256) void gemm_i8(
    const char* __restrict__ Alo, const char* __restrict__ Ahi, int split_row,
    const char* __restrict__ Wq,
    const float* __restrict__ bias, const float* __restrict__ residual,
    void* __restrict__ outp, int M, int N, int K,
    const unsigned int* __restrict__ slotA, float epsA,
    const unsigned int* __restrict__ slotW,
    int apply_gelu, int out_bf16, unsigned int* __restrict__ am_slot)
{
    __shared__ __align__(16) char As0[128*64];
    __shared__ __align__(16) char Ws0[128*64];
    __shared__ __align__(16) char As1[128*64];
    __shared__ __align__(16) char Ws1[128*64];
    __shared__ __align__(16) char As2[128*64];
    __shared__ __align__(16) char Ws2[128*64];
    __shared__ float sred[256];

    float sA  = __uint_as_float(*slotA) / QMAX + epsA;
    float sW  = __uint_as_float(*slotW) / QMAX + 1e-8f;

    const int t    = threadIdx.x;
    const int lane = t & 63;
    const int w    = t >> 6;
    const int wr   = w >> 1;
    const int wc   = w & 1;
    const int lr   = lane & 15;
    const int lk   = lane >> 4;

    const int gx   = gridDim.x;
    const int nwg  = gx * gridDim.y;
    const int wg   = xcd_swizzle(blockIdx.y * gx + blockIdx.x, nwg);
    const int n0   = (wg % gx) * 128;
    const int m0   = (wg / gx) * 128;

    const int rsub = lane >> 2;                          // row within call 0..15
    const int csub = ((lane & 3) ^ ((lane >> 3) & 3)) * 16;  // pre-swizzled src chunk
    const int rchk = (lk ^ ((lr >> 1) & 3)) * 16;        // swizzled read chunk

    int32x4 acc[4][4];
    #pragma unroll
    for (int i = 0; i < 4; ++i)
        #pragma unroll
        for (int j = 0; j < 4; ++j)
            acc[i][j] = (int32x4){0,0,0,0};

    auto STAGE = [&](char* Ab, char* Wb, int kt) {   // exactly 4 VMEM ops per wave
        #pragma unroll
        for (int c = 0; c < 2; ++c) {
            int row  = w*32 + c*16 + rsub;
            int grow = m0 + row;
            if (grow > M-1) grow = M-1;      // clamp (junk only feeds m>=M, skipped)
            const char* base = (grow < split_row) ? Alo : Ahi;
            gload16(base + (size_t)grow*K + kt + csub, Ab + (size_t)(w*32 + c*16)*64);
        }
        #pragma unroll
        for (int c = 0; c < 2; ++c) {
            int row = w*32 + c*16 + rsub;
            gload16(Wq + (size_t)(n0 + row)*K + kt + csub, Wb + (size_t)(w*32 + c*16)*64);
        }
    };
    auto COMPUTE = [&](const char* Ab, const char* Wb) {
        int32x4 af[4], bw[4];
        #pragma unroll
        for (int mi = 0; mi < 4; ++mi)
            af[mi] = *reinterpret_cast<const int32x4*>(
                &Ab[(wr*64 + mi*16 + lr)*64 + rchk]);
        #pragma unroll
        for (int ni = 0; ni < 4; ++ni)
            bw[ni] = *reinterpret_cast<const int32x4*>(
                &Wb[(wc*64 + ni*16 + lr)*64 + rchk]);
        #pragma unroll
        for (int mi = 0; mi < 4; ++mi)
            #pragma unroll
            for (int ni = 0; ni < 4; ++ni)
                acc[mi][ni] = __builtin_amdgcn_mfma_i32_16x16x64_i8(
                    af[mi], bw[ni], acc[mi][ni], 0, 0, 0);
    };

    const int nk = K >> 6;   // 12 or 48: divisible by 3
    STAGE(As0, Ws0, 0);
    STAGE(As1, Ws1, 1 << 6);
    int kt = 0;
    for (; kt + 3 < nk; kt += 3) {
        asm volatile("s_waitcnt vmcnt(4)" ::: "memory");   // buf0 landed (buf1 in flight)
        __builtin_amdgcn_sched_barrier(0);
        __builtin_amdgcn_s_barrier();
        STAGE(As2, Ws2, (kt+2) << 6);
        COMPUTE(As0, Ws0);
        asm volatile("s_waitcnt vmcnt(4)" ::: "memory");   // buf1 landed
        __builtin_amdgcn_sched_barrier(0);
        __builtin_amdgcn_s_barrier();
        STAGE(As0, Ws0, (kt+3) << 6);
        COMPUTE(As1, Ws1);
        asm volatile("s_waitcnt vmcnt(4)" ::: "memory");   // buf2 landed
        __builtin_amdgcn_sched_barrier(0);
        __builtin_amdgcn_s_barrier();
        STAGE(As1, Ws1, (kt+4) << 6);
        COMPUTE(As2, Ws2);
    }
    // final triple (kt == nk-3)
    asm volatile("s_waitcnt vmcnt(4)" ::: "memory");
    __builtin_amdgcn_sched_barrier(0);
    __builtin_amdgcn_s_barrier();
    STAGE(As2, Ws2, (kt+2) << 6);
    COMPUTE(As0, Ws0);
    asm volatile("s_waitcnt vmcnt(4)" ::: "memory");       // buf1 landed, buf2 in flight
    __builtin_amdgcn_sched_barrier(0);
    __builtin_amdgcn_s_barrier();
    COMPUTE(As1, Ws1);
    asm volatile("s_waitcnt vmcnt(0)" ::: "memory");       // drain buf2
    __builtin_amdgcn_sched_barrier(0);
    __builtin_amdgcn_s_barrier();
    COMPUTE(As2, Ws2);

    // ---- epilogue: C/D map col=lane&15, row=(lane>>4)*4+reg ----
    float scale = sA * sW;
    float lmax = 0.f;
    #pragma unroll
    for (int mi = 0; mi < 4; ++mi) {
        #pragma unroll
        for (int j = 0; j < 4; ++j) {
            int m = m0 + wr*64 + mi*16 + lk*4 + j;
            if (m >= M) continue;
            #pragma unroll
            for (int ni = 0; ni < 4; ++ni) {
                int n = n0 + wc*64 + ni*16 + lr;
                float v = scale * (float)acc[mi][ni][j] + bias[n];
                if (residual) v += residual[(size_t)m*N + n];
                if (apply_gelu) v = gelu_fast(v);
                if (out_bf16) {
                    unsigned short ub = f2bf(v);
                    ((unsigned short*)outp)[(size_t)m*N + n] = ub;
                    lmax = fmaxf(lmax, fabsf(bf2f(ub)));
                } else {
                    ((float*)outp)[(size_t)m*N + n] = v;
                    lmax = fmaxf(lmax, fabsf(v));
                }
            }
        }
    }
    if (am_slot) {
        sred[t] = lmax; __syncthreads();
        for (int o = 128; o; o >>= 1) {
            if (t < o) sred[t] = fmaxf(sred[t], sred[t+o]);
            __syncthreads();
        }
        if (t == 0) atomicMax(am_slot, __float_as_uint(sred[0]));
    }
}

// ---------------- MFMA flash attention: swapped QK^T (unchanged from R15) ----------------
__global__ __launch_bounds__(512) void attn_mfma(
    const unsigned short* __restrict__ qkv, unsigned short* __restrict__ xa,
    unsigned int* __restrict__ am_slot)
{
    const int Nn = 577;
    const float SCL2 = 0.125f * 1.44269504088896340736f;
    const int gx = gridDim.x;
    const int wg = xcd_swizzle(blockIdx.y * gx + blockIdx.x, gx * gridDim.y);
    const int q0 = (wg % gx) * 128;
    const int bh = wg / gx;
    const int h  = bh % 12;
    const int b  = bh / 12;
    const int t  = threadIdx.x;
    const int w    = t >> 6;
    const int lane = t & 63;
    const int lr   = lane & 15;
    const int lk   = lane >> 4;

    __shared__ __align__(16) unsigned short Ks[64][72];
    __shared__ __align__(16) unsigned short Vt[64][72];
    __shared__ __align__(16) unsigned short Pw[8][16][72];
    __shared__ float red8[8];

    const size_t rowstride = 2304;
    const size_t basebh = ((size_t)b * Nn) * rowstride + (size_t)h * 64;

    bf16x8 qf[2];
    {
        int row = q0 + w*16 + lr;
        if (row < Nn) {
            const unsigned short* qrow = qkv + (size_t)row * rowstride + basebh;
            qf[0] = *reinterpret_cast<const bf16x8*>(qrow + lk*8);
            qf[1] = *reinterpret_cast<const bf16x8*>(qrow + 32 + lk*8);
        } else {
            #pragma unroll
            for (int j = 0; j < 8; ++j) { qf[0][j] = 0; qf[1][j] = 0; }
        }
    }

    float m_run = -INFINITY, l_run = 0.f;
    f32x4 acc_o[4];
    #pragma unroll
    for (int df = 0; df < 4; ++df) acc_o[df] = (f32x4){0.f,0.f,0.f,0.f};

    for (int kt = 0; kt < 10; ++kt) {
        __syncthreads();
        {
            int r   = t >> 3;
            int e8  = (t & 7) * 8;
            int key = kt*64 + r;
            ushortx8 ku, vu;
            if (key < Nn) {
                const unsigned short* krow = qkv + (size_t)key * rowstride + basebh;
                ku = *reinterpret_cast<const ushortx8*>(krow + 768  + e8);
                vu = *reinterpret_cast<const ushortx8*>(krow + 1536 + e8);
            } else {
                #pragma unroll
                for (int j = 0; j < 8; ++j) { ku[j] = 0; vu[j] = 0; }
            }
            *reinterpret_cast<ushortx8*>(&Ks[r][e8]) = ku;
            int colp = ((((r >> 3) ^ (t & 7)) << 3) | (r & 7));
            #pragma unroll
            for (int j = 0; j < 8; ++j) Vt[e8 + j][colp] = vu[j];
        }
        __syncthreads();

        f32x4 st[4];
        #pragma unroll
        for (int kf = 0; kf < 4; ++kf) st[kf] = (f32x4){0.f,0.f,0.f,0.f};
        __builtin_amdgcn_s_setprio(1);
        #pragma unroll
        for (int kk = 0; kk < 2; ++kk) {
            #pragma unroll
            for (int kf = 0; kf < 4; ++kf) {
                bf16x8 kfrag = *reinterpret_cast<const bf16x8*>(
                    &Ks[kf*16 + lr][kk*32 + lk*8]);
                st[kf] = __builtin_amdgcn_mfma_f32_16x16x32_bf16(
                    kfrag, qf[kk], st[kf], 0, 0, 0);
            }
        }
        __builtin_amdgcn_s_setprio(0);
        #pragma unroll
        for (int kf = 0; kf < 4; ++kf)
            #pragma unroll
            for (int j = 0; j < 4; ++j) {
                int key = kt*64 + kf*16 + lk*4 + j;
                st[kf][j] = (key < Nn) ? st[kf][j] * SCL2 : -INFINITY;
            }

        float tm = st[0][0];
        #pragma unroll
        for (int kf = 0; kf < 4; ++kf)
            #pragma unroll
            for (int j = 0; j < 4; ++j)
                tm = fmaxf(tm, st[kf][j]);
        tm = fmaxf(tm, __shfl_xor(tm, 16));
        tm = fmaxf(tm, __shfl_xor(tm, 32));

        if (__any(tm > m_run + 8.0f)) {
            float nm  = fmaxf(m_run, tm);
            float fac = exp2f(m_run - nm);
            m_run = nm;
            l_run *= fac;
            float facR[4];
            #pragma unroll
            for (int j = 0; j < 4; ++j)
                facR[j] = __shfl(fac, lk*4 + j);
            #pragma unroll
            for (int df = 0; df < 4; ++df)
                #pragma unroll
                for (int j = 0; j < 4; ++j)
                    acc_o[df][j] *= facR[j];
        }

        float ps = 0.f;
        #pragma unroll
        for (int kf = 0; kf < 4; ++kf)
            #pragma unroll
            for (int j = 0; j < 4; ++j) {
                float p = exp2f(st[kf][j] - m_run);
                st[kf][j] = p;
                ps += p;
            }
        ps += __shfl_xor(ps, 16);
        ps += __shfl_xor(ps, 32);
        l_run += ps;

        #pragma unroll
        for (int kf = 0; kf < 4; ++kf)
            #pragma unroll
            for (int j = 0; j < 4; ++j)
                Pw[w][lr][kf*16 + lk*4 + j] = f2bf(st[kf][j]);

        __builtin_amdgcn_s_setprio(1);
        #pragma unroll
        for (int kk = 0; kk < 2; ++kk) {
            bf16x8 pf = *reinterpret_cast<const bf16x8*>(
                &Pw[w][lr][kk*32 + lk*8]);
            #pragma unroll
            for (int df = 0; df < 4; ++df) {
                int ar = df*2 + (lr >> 3);
                bf16x8 vf = *reinterpret_cast<const bf16x8*>(
                    &Vt[df*16 + lr][(((kk*4 + lk) ^ ar) << 3)]);
                acc_o[df] = __builtin_amdgcn_mfma_f32_16x16x32_bf16(
                    pf, vf, acc_o[df], 0, 0, 0);
            }
        }
        __builtin_amdgcn_s_setprio(0);
    }

    float lrow[4];
    #pragma unroll
    for (int j = 0; j < 4; ++j)
        lrow[j] = __shfl(l_run, lk*4 + j);
    float lmax = 0.f;
    #pragma unroll
    for (int j = 0; j < 4; ++j) {
        int m = q0 + w*16 + lk*4 + j;
        if (m < Nn) {
            float rl = 1.0f / lrow[j];
            #pragma unroll
            for (int df = 0; df < 4; ++df) {
                int d = df*16 + lr;
                float o = acc_o[df][j] * rl;
                unsigned short ob = f2bf(o);
                xa[((size_t)(b*Nn + m))*768 + h*64 + d] = ob;
                lmax = fmaxf(lmax, fabsf(bf2f(ob)));
            }
        }
    }
    #pragma unroll
    for (int off = 1; off < 64; off <<= 1)
        lmax = fmaxf(lmax, __shfl_xor(lmax, off));
    if (lane == 0) red8[w] = lmax;
    __syncthreads();
    if (t == 0) {
        float m = 0.f;
        #pragma unroll
        for (int i = 0; i < 8; ++i) m = fmaxf(m, red8[i]);
        atomicMax(am_slot, __float_as_uint(m));
    }
}

extern "C" void kernel_launch(void* const* d_in, const int* in_sizes, int n_in,
                              void* d_out, int out_size, void* d_ws, size_t ws_size,
                              hipStream_t stream)
{
    const float* x      = (const float*)d_in[0];
    const float* ln1_g  = (const float*)d_in[1];
    const float* ln1_b  = (const float*)d_in[2];
    const float* qkv_w  = (const float*)d_in[3];
    const float* qkv_b  = (const float*)d_in[4];
    const float* proj_w = (const float*)d_in[5];
    const float* proj_b = (const float*)d_in[6];
    const float* ln2_g  = (const float*)d_in[7];
    const float* ln2_b  = (const float*)d_in[8];
    const float* fc1_w  = (const float*)d_in[9];
    const float* fc1_b  = (const float*)d_in[10];
    const float* fc2_w  = (const float*)d_in[11];
    const float* fc2_b  = (const float*)d_in[12];
    float* out = (float*)d_out;

    const int B = 32, Nn = 577, C = 768, H3 = 3072;
    const int M = B * Nn;                    // 18464
    const size_t nA = (size_t)M * C;         // 14,180,352
    const size_t nQ = (size_t)M * 3 * C;
    const size_t nH = (size_t)M * H3;        // 56,721,408

    const size_t NEEDED = 256 + 2359296 + nA + 2*nH;
    if (ws_size < NEEDED) return;

    char* wsb = (char*)d_ws;
    unsigned int* am = (unsigned int*)wsb;
    char* WQ  = wsb + 256;
    char* XNQ = WQ + 2359296;                 // int8 slot (ln out / xaq / hq-side)
    char* BIG = XNQ + nA;
    unsigned short* QKV = (unsigned short*)BIG;
    unsigned short* XA  = (unsigned short*)(BIG + 2*nQ);
    unsigned short* Hbf = (unsigned short*)BIG;
    char* HQ = BIG;                           // in-place int8 h (rows >= SPLIT)

    const int SPLIT = 4608;
    const size_t rowsB = 9216 - 4608, rowsC = 18432 - 9216, rowsD = 18464 - 18432;

    dim3 blk(256);
    int mt128 = (M + 127) / 128;

    init_slots<<<dim3(1), dim3(16), 0, stream>>>(am);

    // all 4 weight absmaxes in ONE launch (independent of everything else)
    absmax4_f32<<<dim3(512, 4), blk, 0, stream>>>(
        qkv_w, (size_t)3*C*C, proj_w, (size_t)C*C,
        fc1_w, (size_t)H3*C,  fc2_w, (size_t)C*H3, am + 6);

    // ---- attention branch ----
    ln_absmax<<<dim3(2048), blk, 0, stream>>>(x, ln1_g, ln1_b, M, am + 0);
    ln_quant <<<dim3(2048), blk, 0, stream>>>(x, ln1_g, ln1_b, M, XNQ, am + 0);

    quant_w<<<dim3(1024), blk, 0, stream>>>(qkv_w, WQ, (size_t)3*C*C, am + 6);
    gemm_i8<<<dim3(3*C/128, mt128), blk, 0, stream>>>(
        XNQ, XNQ, 0, WQ, qkv_b, nullptr, QKV, M, 3*C, C,
        am + 0, 2e-8f, am + 6, 0, 1, nullptr);

    attn_mfma<<<dim3(5, 384), dim3(512), 0, stream>>>(QKV, XA, am + 2);

    quant_bf2i8<<<dim3(2048), blk, 0, stream>>>(XA, XNQ, nA/8, am + 2);

    quant_w<<<dim3(1024), blk, 0, stream>>>(proj_w, WQ, (size_t)C*C, am + 7);
    gemm_i8<<<dim3(C/128, mt128), blk, 0, stream>>>(
        XNQ, XNQ, 0, WQ, proj_b, x, out, M, C, C,
        am + 2, 1e-8f, am + 7, 0, 0, nullptr);          // out = x + proj

    // ---- mlp branch ----
    ln_absmax<<<dim3(2048), blk, 0, stream>>>(out, ln2_g, ln2_b, M, am + 4);
    ln_quant <<<dim3(2048), blk, 0, stream>>>(out, ln2_g, ln2_b, M, XNQ, am + 4);

    quant_w<<<dim3(1024), blk, 0, stream>>>(fc1_w, WQ, (size_t)H3*C, am + 8);
    gemm_i8<<<dim3(H3/128, mt128), blk, 0, stream>>>(
        XNQ, XNQ, 0, WQ, fc1_b, nullptr, Hbf, M, H3, C,
        am + 4, 2e-8f, am + 8, 1, 1, am + 3);           // gelu, bf16 h, absmax(h)

    quant_bf2i8<<<dim3(2048), blk, 0, stream>>>(
        Hbf, XNQ, (size_t)SPLIT*H3/8, am + 3);
    quant_bf2i8<<<dim3(2048), blk, 0, stream>>>(
        Hbf + (size_t)4608*H3, HQ + (size_t)4608*H3, rowsB*H3/8, am + 3);
    quant_bf2i8<<<dim3(2048), blk, 0, stream>>>(
        Hbf + (size_t)9216*H3, HQ + (size_t)9216*H3, rowsC*H3/8, am + 3);
    quant_bf2i8<<<dim3(48),  blk, 0, stream>>>(
        Hbf + (size_t)18432*H3, HQ + (size_t)18432*H3, rowsD*H3/8, am + 3);

    quant_w<<<dim3(1024), blk, 0, stream>>>(fc2_w, WQ, (size_t)C*H3, am + 9);
    gemm_i8<<<dim3(C/128, mt128), blk, 0, stream>>>(
        XNQ, HQ, SPLIT, WQ, fc2_b, out, out, M, C, H3,
        am + 3, 1e-8f, am + 9, 0, 0, nullptr);          // out += fc2
}

// Round 24
// 643.821 us; speedup vs baseline: 1.1285x; 1.0762x over previous
//
#include <hip/hip_runtime.h>
#include <hip/hip_bf16.h>
#include <math.h>

#define QMAX 127.0f

// ---- absmax slots (uint-as-float bits) ----
// 0: ln1 y   2: xa(bf16)   3: h(gelu,bf16)   4: ln2 y
// 6: qkv_w   7: proj_w     8: fc1_w          9: fc2_w

typedef unsigned short ushortx8 __attribute__((ext_vector_type(8)));
typedef short bf16x8 __attribute__((ext_vector_type(8)));
typedef float f32x4 __attribute__((ext_vector_type(4)));
typedef int int32x4 __attribute__((ext_vector_type(4)));

__device__ inline float bf2f(unsigned short u) {
    return __uint_as_float(((unsigned int)u) << 16);
}
__device__ inline unsigned short f2bf(float f) {
    __hip_bfloat16 h = __float2bfloat16(f);   // round-to-nearest-even
    return *reinterpret_cast<unsigned short*>(&h);
}

// fast exact-gelu: erf via Abramowitz-Stegun 7.1.26 (|err|<=1.5e-7), branch-free.
__device__ inline float gelu_fast(float v) {
    float z = v * 0.70710678118654752f;
    float a = fabsf(z);
    float t = __builtin_amdgcn_rcpf(fmaf(0.3275911f, a, 1.0f));
    float poly = t * fmaf(t, fmaf(t, fmaf(t, fmaf(t, 1.061405429f, -1.453152027f),
                       1.421413741f), -0.284496736f), 0.254829592f);
    float e = exp2f(-a * a * 1.44269504088896340736f);
    float erfa = 1.0f - poly * e;                 // erf(|z|)
    float erfz = (z < 0.f) ? -erfa : erfa;
    return 0.5f * v * (1.0f + erfz);
}

// async global->LDS DMA: 16B per lane; LDS dest = wave-uniform base + lane*16
__device__ inline void gload16(const char* g, char* l) {
    __builtin_amdgcn_global_load_lds(
        (const __attribute__((address_space(1))) unsigned int*)g,
        (__attribute__((address_space(3))) unsigned int*)l, 16, 0, 0);
}

// bijective XCD-chunked block swizzle (m204)
__device__ inline int xcd_swizzle(int orig, int nwg) {
    int q = nwg >> 3, r = nwg & 7;
    int x = orig & 7, pos = orig >> 3;
    return (x < r ? x * (q + 1) : r * (q + 1) + (x - r) * q) + pos;
}

__global__ void init_slots(unsigned int* am) {
    if (threadIdx.x < 16) am[threadIdx.x] = 0u;
}

// ---------------- merged absmax over 4 fp32 arrays (weights; all independent) ----------------
__global__ __launch_bounds__(256) void absmax4_f32(
    const float* __restrict__ p0, size_t n0, const float* __restrict__ p1, size_t n1,
    const float* __restrict__ p2, size_t n2, const float* __restrict__ p3, size_t n3,
    unsigned int* __restrict__ slots)
{
    const float* p; size_t n;
    switch (blockIdx.y) {
        case 0:  p = p0; n = n0; break;
        case 1:  p = p1; n = n1; break;
        case 2:  p = p2; n = n2; break;
        default: p = p3; n = n3; break;
    }
    float lmax = 0.f;
    for (size_t i = (size_t)blockIdx.x*256 + threadIdx.x; i < n; i += (size_t)gridDim.x*256)
        lmax = fmaxf(lmax, fabsf(p[i]));
    __shared__ float rs[256];
    int t = threadIdx.x;
    rs[t] = lmax; __syncthreads();
    for (int o = 128; o; o >>= 1) {
        if (t < o) rs[t] = fmaxf(rs[t], rs[t+o]);
        __syncthreads();
    }
    if (t == 0) atomicMax(slots + blockIdx.y, __float_as_uint(rs[0]));
}

// ---------------- weight quantize: fp32 -> int8 ----------------
__global__ __launch_bounds__(256) void quant_w(
    const float* __restrict__ w, char* __restrict__ q, size_t n,
    const unsigned int* __restrict__ slot)
{
    float s = __uint_as_float(*slot) / QMAX + 1e-8f;
    for (size_t i = (size_t)blockIdx.x*256 + threadIdx.x; i < n; i += (size_t)gridDim.x*256) {
        float k = fminf(fmaxf(rintf(w[i] / s), -QMAX), QMAX);
        q[i] = (char)(int)k;
    }
}

// ---------------- activation quantize: bf16 -> int8 (8 elems/thread/iter) ----------------
__global__ __launch_bounds__(256) void quant_bf2i8(
    const unsigned short* __restrict__ src, char* __restrict__ dst, size_t n8,
    const unsigned int* __restrict__ slot)
{
    float s  = __uint_as_float(*slot) / QMAX + 1e-8f;
    float rs = 1.0f / s;
    for (size_t i = (size_t)blockIdx.x*256 + threadIdx.x; i < n8; i += (size_t)gridDim.x*256) {
        ushortx8 u = *reinterpret_cast<const ushortx8*>(src + i*8);
        int lo = 0, hi = 0;
        #pragma unroll
        for (int j = 0; j < 4; ++j) {
            int k = (int)fminf(fmaxf(rintf(bf2f(u[j]) * rs), -QMAX), QMAX);
            lo |= (k & 0xff) << (8*j);
        }
        #pragma unroll
        for (int j = 0; j < 4; ++j) {
            int k = (int)fminf(fmaxf(rintf(bf2f(u[4+j]) * rs), -QMAX), QMAX);
            hi |= (k & 0xff) << (8*j);
        }
        reinterpret_cast<int2*>(dst)[i] = make_int2(lo, hi);
    }
}

// ---------------- LayerNorm pass 1: absmax(y), wave-per-row ----------------
__global__ __launch_bounds__(256) void ln_absmax(
    const float* __restrict__ x, const float* __restrict__ g, const float* __restrict__ bia,
    int nrows, unsigned int* __restrict__ slot)
{
    const int lane = threadIdx.x & 63;
    const int wv   = threadIdx.x >> 6;
    int wid = blockIdx.x*4 + wv;
    int nw  = gridDim.x*4;
    const float4* g4 = reinterpret_cast<const float4*>(g);
    const float4* b4 = reinterpret_cast<const float4*>(bia);
    float4 ga = g4[lane], gb = g4[lane+64], gc = g4[lane+128];
    float4 ba = b4[lane], bb = b4[lane+64], bc = b4[lane+128];
    float wmax = 0.f;
    for (int row = wid; row < nrows; row += nw) {
        const float4* xr = reinterpret_cast<const float4*>(x + (size_t)row*768);
        float4 xa = xr[lane], xb = xr[lane+64], xc = xr[lane+128];
        float s  = xa.x+xa.y+xa.z+xa.w + xb.x+xb.y+xb.z+xb.w + xc.x+xc.y+xc.z+xc.w;
        float ss = xa.x*xa.x+xa.y*xa.y+xa.z*xa.z+xa.w*xa.w
                 + xb.x*xb.x+xb.y*xb.y+xb.z*xb.z+xb.w*xb.w
                 + xc.x*xc.x+xc.y*xc.y+xc.z*xc.z+xc.w*xc.w;
        #pragma unroll
        for (int off = 32; off; off >>= 1) {
            s  += __shfl_xor(s,  off);
            ss += __shfl_xor(ss, off);
        }
        float mean = s * (1.0f/768.0f);
        float inv  = rsqrtf(ss * (1.0f/768.0f) - mean*mean + 1e-6f);
        float m = 0.f;
        m = fmaxf(m, fabsf((xa.x-mean)*inv*ga.x + ba.x));
        m = fmaxf(m, fabsf((xa.y-mean)*inv*ga.y + ba.y));
        m = fmaxf(m, fabsf((xa.z-mean)*inv*ga.z + ba.z));
        m = fmaxf(m, fabsf((xa.w-mean)*inv*ga.w + ba.w));
        m = fmaxf(m, fabsf((xb.x-mean)*inv*gb.x + bb.x));
        m = fmaxf(m, fabsf((xb.y-mean)*inv*gb.y + bb.y));
        m = fmaxf(m, fabsf((xb.z-mean)*inv*gb.z + bb.z));
        m = fmaxf(m, fabsf((xb.w-mean)*inv*gb.w + bb.w));
        m = fmaxf(m, fabsf((xc.x-mean)*inv*gc.x + bc.x));
        m = fmaxf(m, fabsf((xc.y-mean)*inv*gc.y + bc.y));
        m = fmaxf(m, fabsf((xc.z-mean)*inv*gc.z + bc.z));
        m = fmaxf(m, fabsf((xc.w-mean)*inv*gc.w + bc.w));
        wmax = fmaxf(wmax, m);
    }
    #pragma unroll
    for (int off = 32; off; off >>= 1)
        wmax = fmaxf(wmax, __shfl_xor(wmax, off));
    __shared__ float red[4];
    if (lane == 0) red[wv] = wmax;
    __syncthreads();
    if (threadIdx.x == 0) {
        float m = fmaxf(fmaxf(red[0], red[1]), fmaxf(red[2], red[3]));
        atomicMax(slot, __float_as_uint(m));
    }
}

// ---------------- LayerNorm pass 2: wave-per-row, emit packed int8 ----------------
__global__ __launch_bounds__(256) void ln_quant(
    const float* __restrict__ x, const float* __restrict__ g, const float* __restrict__ bia,
    int nrows, char* __restrict__ yq, const unsigned int* __restrict__ slot)
{
    const int lane = threadIdx.x & 63;
    const int wv   = threadIdx.x >> 6;
    int wid = blockIdx.x*4 + wv;
    int nw  = gridDim.x*4;
    const float4* g4 = reinterpret_cast<const float4*>(g);
    const float4* b4 = reinterpret_cast<const float4*>(bia);
    float4 ga = g4[lane], gb = g4[lane+64], gc = g4[lane+128];
    float4 ba = b4[lane], bb = b4[lane+64], bc = b4[lane+128];
    float s1 = __uint_as_float(*slot) / QMAX + 1e-8f;
    float r1 = 1.0f / s1;
    for (int row = wid; row < nrows; row += nw) {
        const float4* xr = reinterpret_cast<const float4*>(x + (size_t)row*768);
        float4 xa = xr[lane], xb = xr[lane+64], xc = xr[lane+128];
        float s  = xa.x+xa.y+xa.z+xa.w + xb.x+xb.y+xb.z+xb.w + xc.x+xc.y+xc.z+xc.w;
        float ss = xa.x*xa.x+xa.y*xa.y+xa.z*xa.z+xa.w*xa.w
                 + xb.x*xb.x+xb.y*xb.y+xb.z*xb.z+xb.w*xb.w
                 + xc.x*xc.x+xc.y*xc.y+xc.z*xc.z+xc.w*xc.w;
        #pragma unroll
        for (int off = 32; off; off >>= 1) {
            s  += __shfl_xor(s,  off);
            ss += __shfl_xor(ss, off);
        }
        float mean = s * (1.0f/768.0f);
        float inv  = rsqrtf(ss * (1.0f/768.0f) - mean*mean + 1e-6f);
        int* yr = reinterpret_cast<int*>(yq + (size_t)row*768);
        float y0, y1, y2, y3;
        int p;
        y0 = (xa.x-mean)*inv*ga.x + ba.x; y1 = (xa.y-mean)*inv*ga.y + ba.y;
        y2 = (xa.z-mean)*inv*ga.z + ba.z; y3 = (xa.w-mean)*inv*ga.w + ba.w;
        p  = ((int)fminf(fmaxf(rintf(y0*r1), -QMAX), QMAX) & 0xff)
           | (((int)fminf(fmaxf(rintf(y1*r1), -QMAX), QMAX) & 0xff) << 8)
           | (((int)fminf(fmaxf(rintf(y2*r1), -QMAX), QMAX) & 0xff) << 16)
           | (((int)fminf(fmaxf(rintf(y3*r1), -QMAX), QMAX) & 0xff) << 24);
        yr[lane] = p;
        y0 = (xb.x-mean)*inv*gb.x + bb.x; y1 = (xb.y-mean)*inv*gb.y + bb.y;
        y2 = (xb.z-mean)*inv*gb.z + bb.z; y3 = (xb.w-mean)*inv*gb.w + bb.w;
        p  = ((int)fminf(fmaxf(rintf(y0*r1), -QMAX), QMAX) & 0xff)
           | (((int)fminf(fmaxf(rintf(y1*r1), -QMAX), QMAX) & 0xff) << 8)
           | (((int)fminf(fmaxf(rintf(y2*r1), -QMAX), QMAX) & 0xff) << 16)
           | (((int)fminf(fmaxf(rintf(y3*r1), -QMAX), QMAX) & 0xff) << 24);
        yr[lane+64] = p;
        y0 = (xc.x-mean)*inv*gc.x + bc.x; y1 = (xc.y-mean)*inv*gc.y + bc.y;
        y2 = (xc.z-mean)*inv*gc.z + bc.z; y3 = (xc.w-mean)*inv*gc.w + bc.w;
        p  = ((int)fminf(fmaxf(rintf(y0*r1), -QMAX), QMAX) & 0xff)
           | (((int)fminf(fmaxf(rintf(y1*r1), -QMAX), QMAX) & 0xff) << 8)
           | (((int)fminf(fmaxf(rintf(y2*r1), -QMAX), QMAX) & 0xff) << 16)
           | (((int)fminf(fmaxf(rintf(y3*r1), -QMAX), QMAX) & 0xff) << 24);
        yr[lane+128] = p;
    }
}

// ---------------- int8 MFMA GEMM: BM=64 tile, ring-3, 4 blocks/CU ----------------
// Per-iter stall (~4800 cyc/block) is latency-pool-bound: gload_lds completion
// far exceeds depth-2 cover, and 2.4 blocks/CU gave too few independent
// pipelines. BM=64 (wave = 64x32, acc 4x2) cuts LDS to 37KB -> 4 blocks/CU
// and doubles grid (fc2 tail 1.4 -> 2.3 rounds of smaller blocks).
// STAGE = 3 vmem/wave -> vmcnt(3). Same validated chunk swizzle; integer
// accumulation is order-independent -> bit-identical output.
__global__ __launch_bounds__(256) void gemm_i8(
    const char* __restrict__ Alo, const char* __restrict__ Ahi, int split_row,
    const char* __restrict__ Wq,
    const float* __restrict__ bias, const float* __restrict__ residual,
    void* __restrict__ outp, int M, int N, int K,
    const unsigned int* __restrict__ slotA, float epsA,
    const unsigned int* __restrict__ slotW,
    int apply_gelu, int out_bf16, unsigned int* __restrict__ am_slot)
{
    __shared__ __align__(16) char As0[64*64];
    __shared__ __align__(16) char Ws0[128*64];
    __shared__ __align__(16) char As1[64*64];
    __shared__ __align__(16) char Ws1[128*64];
    __shared__ __align__(16) char As2[64*64];
    __shared__ __align__(16) char Ws2[128*64];
    __shared__ float sred[256];

    float sA  = __uint_as_float(*slotA) / QMAX + epsA;
    float sW  = __uint_as_float(*slotW) / QMAX + 1e-8f;

    const int t    = threadIdx.x;
    const int lane = t & 63;
    const int w    = t >> 6;        // wave 0..3: owns cols w*32..+32
    const int lr   = lane & 15;
    const int lk   = lane >> 4;

    const int gx   = gridDim.x;
    const int nwg  = gx * gridDim.y;
    const int wg   = xcd_swizzle(blockIdx.y * gx + blockIdx.x, nwg);
    const int n0   = (wg % gx) * 128;
    const int m0   = (wg / gx) * 64;

    const int rsub = lane >> 2;                          // row within call 0..15
    const int csub = ((lane & 3) ^ ((lane >> 3) & 3)) * 16;  // pre-swizzled src chunk
    const int rchk = (lk ^ ((lr >> 1) & 3)) * 16;        // swizzled read chunk

    int32x4 acc[4][2];
    #pragma unroll
    for (int i = 0; i < 4; ++i)
        #pragma unroll
        for (int j = 0; j < 2; ++j)
            acc[i][j] = (int32x4){0,0,0,0};

    auto STAGE = [&](char* Ab, char* Wb, int kt) {   // exactly 3 VMEM ops per wave
        {   // A: wave stages rows [w*16, w*16+16)
            int grow = m0 + w*16 + rsub;
            if (grow > M-1) grow = M-1;      // clamp (junk only feeds m>=M, skipped)
            const char* base = (grow < split_row) ? Alo : Ahi;
            gload16(base + (size_t)grow*K + kt + csub, Ab + (size_t)(w*16)*64);
        }
        #pragma unroll
        for (int c = 0; c < 2; ++c) {        // W: wave stages rows [w*32, w*32+32)
            int row = w*32 + c*16 + rsub;
            gload16(Wq + (size_t)(n0 + row)*K + kt + csub, Wb + (size_t)(w*32 + c*16)*64);
        }
    };
    auto COMPUTE = [&](const char* Ab, const char* Wb) {
        int32x4 af[4], bw[2];
        #pragma unroll
        for (int mi = 0; mi < 4; ++mi)
            af[mi] = *reinterpret_cast<const int32x4*>(
                &Ab[(mi*16 + lr)*64 + rchk]);
        #pragma unroll
        for (int ni = 0; ni < 2; ++ni)
            bw[ni] = *reinterpret_cast<const int32x4*>(
                &Wb[(w*32 + ni*16 + lr)*64 + rchk]);
        #pragma unroll
        for (int mi = 0; mi < 4; ++mi)
            #pragma unroll
            for (int ni = 0; ni < 2; ++ni)
                acc[mi][ni] = __builtin_amdgcn_mfma_i32_16x16x64_i8(
                    af[mi], bw[ni], acc[mi][ni], 0, 0, 0);
    };

    const int nk = K >> 6;   // 12 or 48: divisible by 3
    STAGE(As0, Ws0, 0);
    STAGE(As1, Ws1, 1 << 6);
    int kt = 0;
    for (; kt + 3 < nk; kt += 3) {
        asm volatile("s_waitcnt vmcnt(3)" ::: "memory");   // buf0 landed (buf1 in flight)
        __builtin_amdgcn_sched_barrier(0);
        __builtin_amdgcn_s_barrier();
        STAGE(As2, Ws2, (kt+2) << 6);
        COMPUTE(As0, Ws0);
        asm volatile("s_waitcnt vmcnt(3)" ::: "memory");   // buf1 landed
        __builtin_amdgcn_sched_barrier(0);
        __builtin_amdgcn_s_barrier();
        STAGE(As0, Ws0, (kt+3) << 6);
        COMPUTE(As1, Ws1);
        asm volatile("s_waitcnt vmcnt(3)" ::: "memory");   // buf2 landed
        __builtin_amdgcn_sched_barrier(0);
        __builtin_amdgcn_s_barrier();
        STAGE(As1, Ws1, (kt+4) << 6);
        COMPUTE(As2, Ws2);
    }
    // final triple (kt == nk-3)
    asm volatile("s_waitcnt vmcnt(3)" ::: "memory");
    __builtin_amdgcn_sched_barrier(0);
    __builtin_amdgcn_s_barrier();
    STAGE(As2, Ws2, (kt+2) << 6);
    COMPUTE(As0, Ws0);
    asm volatile("s_waitcnt vmcnt(3)" ::: "memory");       // buf1 landed, buf2 in flight
    __builtin_amdgcn_sched_barrier(0);
    __builtin_amdgcn_s_barrier();
    COMPUTE(As1, Ws1);
    asm volatile("s_waitcnt vmcnt(0)" ::: "memory");       // drain buf2
    __builtin_amdgcn_sched_barrier(0);
    __builtin_amdgcn_s_barrier();
    COMPUTE(As2, Ws2);

    // ---- epilogue: C/D map col=lane&15, row=(lane>>4)*4+reg ----
    float scale = sA * sW;
    float lmax = 0.f;
    #pragma unroll
    for (int mi = 0; mi < 4; ++mi) {
        #pragma unroll
        for (int j = 0; j < 4; ++j) {
            int m = m0 + mi*16 + lk*4 + j;
            if (m >= M) continue;
            #pragma unroll
            for (int ni = 0; ni < 2; ++ni) {
                int n = n0 + w*32 + ni*16 + lr;
                float v = scale * (float)acc[mi][ni][j] + bias[n];
                if (residual) v += residual[(size_t)m*N + n];
                if (apply_gelu) v = gelu_fast(v);
                if (out_bf16) {
                    unsigned short ub = f2bf(v);
                    ((unsigned short*)outp)[(size_t)m*N + n] = ub;
                    lmax = fmaxf(lmax, fabsf(bf2f(ub)));
                } else {
                    ((float*)outp)[(size_t)m*N + n] = v;
                    lmax = fmaxf(lmax, fabsf(v));
                }
            }
        }
    }
    if (am_slot) {
        sred[t] = lmax; __syncthreads();
        for (int o = 128; o; o >>= 1) {
            if (t < o) sred[t] = fmaxf(sred[t], sred[t+o]);
            __syncthreads();
        }
        if (t == 0) atomicMax(am_slot, __float_as_uint(sred[0]));
    }
}

// ---------------- MFMA flash attention: swapped QK^T (unchanged from R15) ----------------
__global__ __launch_bounds__(512) void attn_mfma(
    const unsigned short* __restrict__ qkv, unsigned short* __restrict__ xa,
    unsigned int* __restrict__ am_slot)
{
    const int Nn = 577;
    const float SCL2 = 0.125f * 1.44269504088896340736f;
    const int gx = gridDim.x;
    const int wg = xcd_swizzle(blockIdx.y * gx + blockIdx.x, gx * gridDim.y);
    const int q0 = (wg % gx) * 128;
    const int bh = wg / gx;
    const int h  = bh % 12;
    const int b  = bh / 12;
    const int t  = threadIdx.x;
    const int w    = t >> 6;
    const int lane = t & 63;
    const int lr   = lane & 15;
    const int lk   = lane >> 4;

    __shared__ __align__(16) unsigned short Ks[64][72];
    __shared__ __align__(16) unsigned short Vt[64][72];
    __shared__ __align__(16) unsigned short Pw[8][16][72];
    __shared__ float red8[8];

    const size_t rowstride = 2304;
    const size_t basebh = ((size_t)b * Nn) * rowstride + (size_t)h * 64;

    bf16x8 qf[2];
    {
        int row = q0 + w*16 + lr;
        if (row < Nn) {
            const unsigned short* qrow = qkv + (size_t)row * rowstride + basebh;
            qf[0] = *reinterpret_cast<const bf16x8*>(qrow + lk*8);
            qf[1] = *reinterpret_cast<const bf16x8*>(qrow + 32 + lk*8);
        } else {
            #pragma unroll
            for (int j = 0; j < 8; ++j) { qf[0][j] = 0; qf[1][j] = 0; }
        }
    }

    float m_run = -INFINITY, l_run = 0.f;
    f32x4 acc_o[4];
    #pragma unroll
    for (int df = 0; df < 4; ++df) acc_o[df] = (f32x4){0.f,0.f,0.f,0.f};

    for (int kt = 0; kt < 10; ++kt) {
        __syncthreads();
        {
            int r   = t >> 3;
            int e8  = (t & 7) * 8;
            int key = kt*64 + r;
            ushortx8 ku, vu;
            if (key < Nn) {
                const unsigned short* krow = qkv + (size_t)key * rowstride + basebh;
                ku = *reinterpret_cast<const ushortx8*>(krow + 768  + e8);
                vu = *reinterpret_cast<const ushortx8*>(krow + 1536 + e8);
            } else {
                #pragma unroll
                for (int j = 0; j < 8; ++j) { ku[j] = 0; vu[j] = 0; }
            }
            *reinterpret_cast<ushortx8*>(&Ks[r][e8]) = ku;
            int colp = ((((r >> 3) ^ (t & 7)) << 3) | (r & 7));
            #pragma unroll
            for (int j = 0; j < 8; ++j) Vt[e8 + j][colp] = vu[j];
        }
        __syncthreads();

        f32x4 st[4];
        #pragma unroll
        for (int kf = 0; kf < 4; ++kf) st[kf] = (f32x4){0.f,0.f,0.f,0.f};
        __builtin_amdgcn_s_setprio(1);
        #pragma unroll
        for (int kk = 0; kk < 2; ++kk) {
            #pragma unroll
            for (int kf = 0; kf < 4; ++kf) {
                bf16x8 kfrag = *reinterpret_cast<const bf16x8*>(
                    &Ks[kf*16 + lr][kk*32 + lk*8]);
                st[kf] = __builtin_amdgcn_mfma_f32_16x16x32_bf16(
                    kfrag, qf[kk], st[kf], 0, 0, 0);
            }
        }
        __builtin_amdgcn_s_setprio(0);
        #pragma unroll
        for (int kf = 0; kf < 4; ++kf)
            #pragma unroll
            for (int j = 0; j < 4; ++j) {
                int key = kt*64 + kf*16 + lk*4 + j;
                st[kf][j] = (key < Nn) ? st[kf][j] * SCL2 : -INFINITY;
            }

        float tm = st[0][0];
        #pragma unroll
        for (int kf = 0; kf < 4; ++kf)
            #pragma unroll
            for (int j = 0; j < 4; ++j)
                tm = fmaxf(tm, st[kf][j]);
        tm = fmaxf(tm, __shfl_xor(tm, 16));
        tm = fmaxf(tm, __shfl_xor(tm, 32));

        if (__any(tm > m_run + 8.0f)) {
            float nm  = fmaxf(m_run, tm);
            float fac = exp2f(m_run - nm);
            m_run = nm;
            l_run *= fac;
            float facR[4];
            #pragma unroll
            for (int j = 0; j < 4; ++j)
                facR[j] = __shfl(fac, lk*4 + j);
            #pragma unroll
            for (int df = 0; df < 4; ++df)
                #pragma unroll
                for (int j = 0; j < 4; ++j)
                    acc_o[df][j] *= facR[j];
        }

        float ps = 0.f;
        #pragma unroll
        for (int kf = 0; kf < 4; ++kf)
            #pragma unroll
            for (int j = 0; j < 4; ++j) {
                float p = exp2f(st[kf][j] - m_run);
                st[kf][j] = p;
                ps += p;
            }
        ps += __shfl_xor(ps, 16);
        ps += __shfl_xor(ps, 32);
        l_run += ps;

        #pragma unroll
        for (int kf = 0; kf < 4; ++kf)
            #pragma unroll
            for (int j = 0; j < 4; ++j)
                Pw[w][lr][kf*16 + lk*4 + j] = f2bf(st[kf][j]);

        __builtin_amdgcn_s_setprio(1);
        #pragma unroll
        for (int kk = 0; kk < 2; ++kk) {
            bf16x8 pf = *reinterpret_cast<const bf16x8*>(
                &Pw[w][lr][kk*32 + lk*8]);
            #pragma unroll
            for (int df = 0; df < 4; ++df) {
                int ar = df*2 + (lr >> 3);
                bf16x8 vf = *reinterpret_cast<const bf16x8*>(
                    &Vt[df*16 + lr][(((kk*4 + lk) ^ ar) << 3)]);
                acc_o[df] = __builtin_amdgcn_mfma_f32_16x16x32_bf16(
                    pf, vf, acc_o[df], 0, 0, 0);
            }
        }
        __builtin_amdgcn_s_setprio(0);
    }

    float lrow[4];
    #pragma unroll
    for (int j = 0; j < 4; ++j)
        lrow[j] = __shfl(l_run, lk*4 + j);
    float lmax = 0.f;
    #pragma unroll
    for (int j = 0; j < 4; ++j) {
        int m = q0 + w*16 + lk*4 + j;
        if (m < Nn) {
            float rl = 1.0f / lrow[j];
            #pragma unroll
            for (int df = 0; df < 4; ++df) {
                int d = df*16 + lr;
                float o = acc_o[df][j] * rl;
                unsigned short ob = f2bf(o);
                xa[((size_t)(b*Nn + m))*768 + h*64 + d] = ob;
                lmax = fmaxf(lmax, fabsf(bf2f(ob)));
            }
        }
    }
    #pragma unroll
    for (int off = 1; off < 64; off <<= 1)
        lmax = fmaxf(lmax, __shfl_xor(lmax, off));
    if (lane == 0) red8[w] = lmax;
    __syncthreads();
    if (t == 0) {
        float m = 0.f;
        #pragma unroll
        for (int i = 0; i < 8; ++i) m = fmaxf(m, red8[i]);
        atomicMax(am_slot, __float_as_uint(m));
    }
}

extern "C" void kernel_launch(void* const* d_in, const int* in_sizes, int n_in,
                              void* d_out, int out_size, void* d_ws, size_t ws_size,
                              hipStream_t stream)
{
    const float* x      = (const float*)d_in[0];
    const float* ln1_g  = (const float*)d_in[1];
    const float* ln1_b  = (const float*)d_in[2];
    const float* qkv_w  = (const float*)d_in[3];
    const float* qkv_b  = (const float*)d_in[4];
    const float* proj_w = (const float*)d_in[5];
    const float* proj_b = (const float*)d_in[6];
    const float* ln2_g  = (const float*)d_in[7];
    const float* ln2_b  = (const float*)d_in[8];
    const float* fc1_w  = (const float*)d_in[9];
    const float* fc1_b  = (const float*)d_in[10];
    const float* fc2_w  = (const float*)d_in[11];
    const float* fc2_b  = (const float*)d_in[12];
    float* out = (float*)d_out;

    const int B = 32, Nn = 577, C = 768, H3 = 3072;
    const int M = B * Nn;                    // 18464
    const size_t nA = (size_t)M * C;         // 14,180,352
    const size_t nQ = (size_t)M * 3 * C;
    const size_t nH = (size_t)M * H3;        // 56,721,408

    const size_t NEEDED = 256 + 2359296 + nA + 2*nH;
    if (ws_size < NEEDED) return;

    char* wsb = (char*)d_ws;
    unsigned int* am = (unsigned int*)wsb;
    char* WQ  = wsb + 256;
    char* XNQ = WQ + 2359296;                 // int8 slot (ln out / xaq / hq-side)
    char* BIG = XNQ + nA;
    unsigned short* QKV = (unsigned short*)BIG;
    unsigned short* XA  = (unsigned short*)(BIG + 2*nQ);
    unsigned short* Hbf = (unsigned short*)BIG;
    char* HQ = BIG;                           // in-place int8 h (rows >= SPLIT)

    const int SPLIT = 4608;
    const size_t rowsB = 9216 - 4608, rowsC = 18432 - 9216, rowsD = 18464 - 18432;

    dim3 blk(256);
    int mt64 = (M + 63) / 64;    // 289

    init_slots<<<dim3(1), dim3(16), 0, stream>>>(am);

    // all 4 weight absmaxes in ONE launch (independent of everything else)
    absmax4_f32<<<dim3(512, 4), blk, 0, stream>>>(
        qkv_w, (size_t)3*C*C, proj_w, (size_t)C*C,
        fc1_w, (size_t)H3*C,  fc2_w, (size_t)C*H3, am + 6);

    // ---- attention branch ----
    ln_absmax<<<dim3(2048), blk, 0, stream>>>(x, ln1_g, ln1_b, M, am + 0);
    ln_quant <<<dim3(2048), blk, 0, stream>>>(x, ln1_g, ln1_b, M, XNQ, am + 0);

    quant_w<<<dim3(1024), blk, 0, stream>>>(qkv_w, WQ, (size_t)3*C*C, am + 6);
    gemm_i8<<<dim3(3*C/128, mt64), blk, 0, stream>>>(
        XNQ, XNQ, 0, WQ, qkv_b, nullptr, QKV, M, 3*C, C,
        am + 0, 2e-8f, am + 6, 0, 1, nullptr);

    attn_mfma<<<dim3(5, 384), dim3(512), 0, stream>>>(QKV, XA, am + 2);

    quant_bf2i8<<<dim3(2048), blk, 0, stream>>>(XA, XNQ, nA/8, am + 2);

    quant_w<<<dim3(1024), blk, 0, stream>>>(proj_w, WQ, (size_t)C*C, am + 7);
    gemm_i8<<<dim3(C/128, mt64), blk, 0, stream>>>(
        XNQ, XNQ, 0, WQ, proj_b, x, out, M, C, C,
        am + 2, 1e-8f, am + 7, 0, 0, nullptr);          // out = x + proj

    // ---- mlp branch ----
    ln_absmax<<<dim3(2048), blk, 0, stream>>>(out, ln2_g, ln2_b, M, am + 4);
    ln_quant <<<dim3(2048), blk, 0, stream>>>(out, ln2_g, ln2_b, M, XNQ, am + 4);

    quant_w<<<dim3(1024), blk, 0, stream>>>(fc1_w, WQ, (size_t)H3*C, am + 8);
    gemm_i8<<<dim3(H3/128, mt64), blk, 0, stream>>>(
        XNQ, XNQ, 0, WQ, fc1_b, nullptr, Hbf, M, H3, C,
        am + 4, 2e-8f, am + 8, 1, 1, am + 3);           // gelu, bf16 h, absmax(h)

    quant_bf2i8<<<dim3(2048), blk, 0, stream>>>(
        Hbf, XNQ, (size_t)SPLIT*H3/8, am + 3);
    quant_bf2i8<<<dim3(2048), blk, 0, stream>>>(
        Hbf + (size_t)4608*H3, HQ + (size_t)4608*H3, rowsB*H3/8, am + 3);
    quant_bf2i8<<<dim3(2048), blk, 0, stream>>>(
        Hbf + (size_t)9216*H3, HQ + (size_t)9216*H3, rowsC*H3/8, am + 3);
    quant_bf2i8<<<dim3(48),  blk, 0, stream>>>(
        Hbf + (size_t)18432*H3, HQ + (size_t)18432*H3, rowsD*H3/8, am + 3);

    quant_w<<<dim3(1024), blk, 0, stream>>>(fc2_w, WQ, (size_t)C*H3, am + 9);
    gemm_i8<<<dim3(C/128, mt64), blk, 0, stream>>>(
        XNQ, HQ, SPLIT, WQ, fc2_b, out, out, M, C, H3,
        am + 3, 1e-8f, am + 9, 0, 0, nullptr);          // out += fc2
}

// Round 25
// 640.479 us; speedup vs baseline: 1.1344x; 1.0052x over previous
//
#include <hip/hip_runtime.h>
#include <hip/hip_bf16.h>
#include <math.h>

#define QMAX 127.0f

// ---- absmax slots (uint-as-float bits) ----
// 0: ln1 y   2: xa(bf16)   3: h(gelu,bf16)   4: ln2 y
// 6: qkv_w   7: proj_w     8: fc1_w          9: fc2_w

typedef unsigned short ushortx8 __attribute__((ext_vector_type(8)));
typedef short bf16x8 __attribute__((ext_vector_type(8)));
typedef float f32x4 __attribute__((ext_vector_type(4)));
typedef int int32x4 __attribute__((ext_vector_type(4)));

__device__ inline float bf2f(unsigned short u) {
    return __uint_as_float(((unsigned int)u) << 16);
}
__device__ inline unsigned short f2bf(float f) {
    __hip_bfloat16 h = __float2bfloat16(f);   // round-to-nearest-even
    return *reinterpret_cast<unsigned short*>(&h);
}

// fast exact-gelu: erf via Abramowitz-Stegun 7.1.26 (|err|<=1.5e-7), branch-free.
__device__ inline float gelu_fast(float v) {
    float z = v * 0.70710678118654752f;
    float a = fabsf(z);
    float t = __builtin_amdgcn_rcpf(fmaf(0.3275911f, a, 1.0f));
    float poly = t * fmaf(t, fmaf(t, fmaf(t, fmaf(t, 1.061405429f, -1.453152027f),
                       1.421413741f), -0.284496736f), 0.254829592f);
    float e = exp2f(-a * a * 1.44269504088896340736f);
    float erfa = 1.0f - poly * e;                 // erf(|z|)
    float erfz = (z < 0.f) ? -erfa : erfa;
    return 0.5f * v * (1.0f + erfz);
}

// async global->LDS DMA: 16B per lane; LDS dest = wave-uniform base + lane*16
__device__ inline void gload16(const char* g, char* l) {
    __builtin_amdgcn_global_load_lds(
        (const __attribute__((address_space(1))) unsigned int*)g,
        (__attribute__((address_space(3))) unsigned int*)l, 16, 0, 0);
}

// bijective XCD-chunked block swizzle (m204)
__device__ inline int xcd_swizzle(int orig, int nwg) {
    int q = nwg >> 3, r = nwg & 7;
    int x = orig & 7, pos = orig >> 3;
    return (x < r ? x * (q + 1) : r * (q + 1) + (x - r) * q) + pos;
}

__global__ void init_slots(unsigned int* am) {
    if (threadIdx.x < 16) am[threadIdx.x] = 0u;
}

// ---------------- merged absmax over 4 fp32 arrays (weights; all independent) ----------------
__global__ __launch_bounds__(256) void absmax4_f32(
    const float* __restrict__ p0, size_t n0, const float* __restrict__ p1, size_t n1,
    const float* __restrict__ p2, size_t n2, const float* __restrict__ p3, size_t n3,
    unsigned int* __restrict__ slots)
{
    const float* p; size_t n;
    switch (blockIdx.y) {
        case 0:  p = p0; n = n0; break;
        case 1:  p = p1; n = n1; break;
        case 2:  p = p2; n = n2; break;
        default: p = p3; n = n3; break;
    }
    float lmax = 0.f;
    for (size_t i = (size_t)blockIdx.x*256 + threadIdx.x; i < n; i += (size_t)gridDim.x*256)
        lmax = fmaxf(lmax, fabsf(p[i]));
    __shared__ float rs[256];
    int t = threadIdx.x;
    rs[t] = lmax; __syncthreads();
    for (int o = 128; o; o >>= 1) {
        if (t < o) rs[t] = fmaxf(rs[t], rs[t+o]);
        __syncthreads();
    }
    if (t == 0) atomicMax(slots + blockIdx.y, __float_as_uint(rs[0]));
}

// ---------------- weight quantize: fp32 -> int8 ----------------
__global__ __launch_bounds__(256) void quant_w(
    const float* __restrict__ w, char* __restrict__ q, size_t n,
    const unsigned int* __restrict__ slot)
{
    float s = __uint_as_float(*slot) / QMAX + 1e-8f;
    for (size_t i = (size_t)blockIdx.x*256 + threadIdx.x; i < n; i += (size_t)gridDim.x*256) {
        float k = fminf(fmaxf(rintf(w[i] / s), -QMAX), QMAX);
        q[i] = (char)(int)k;
    }
}

// ---------------- activation quantize: bf16 -> int8 (8 elems/thread/iter) ----------------
__global__ __launch_bounds__(256) void quant_bf2i8(
    const unsigned short* __restrict__ src, char* __restrict__ dst, size_t n8,
    const unsigned int* __restrict__ slot)
{
    float s  = __uint_as_float(*slot) / QMAX + 1e-8f;
    float rs = 1.0f / s;
    for (size_t i = (size_t)blockIdx.x*256 + threadIdx.x; i < n8; i += (size_t)gridDim.x*256) {
        ushortx8 u = *reinterpret_cast<const ushortx8*>(src + i*8);
        int lo = 0, hi = 0;
        #pragma unroll
        for (int j = 0; j < 4; ++j) {
            int k = (int)fminf(fmaxf(rintf(bf2f(u[j]) * rs), -QMAX), QMAX);
            lo |= (k & 0xff) << (8*j);
        }
        #pragma unroll
        for (int j = 0; j < 4; ++j) {
            int k = (int)fminf(fmaxf(rintf(bf2f(u[4+j]) * rs), -QMAX), QMAX);
            hi |= (k & 0xff) << (8*j);
        }
        reinterpret_cast<int2*>(dst)[i] = make_int2(lo, hi);
    }
}

// ---------------- LayerNorm pass 1: absmax(y), wave-per-row ----------------
__global__ __launch_bounds__(256) void ln_absmax(
    const float* __restrict__ x, const float* __restrict__ g, const float* __restrict__ bia,
    int nrows, unsigned int* __restrict__ slot)
{
    const int lane = threadIdx.x & 63;
    const int wv   = threadIdx.x >> 6;
    int wid = blockIdx.x*4 + wv;
    int nw  = gridDim.x*4;
    const float4* g4 = reinterpret_cast<const float4*>(g);
    const float4* b4 = reinterpret_cast<const float4*>(bia);
    float4 ga = g4[lane], gb = g4[lane+64], gc = g4[lane+128];
    float4 ba = b4[lane], bb = b4[lane+64], bc = b4[lane+128];
    float wmax = 0.f;
    for (int row = wid; row < nrows; row += nw) {
        const float4* xr = reinterpret_cast<const float4*>(x + (size_t)row*768);
        float4 xa = xr[lane], xb = xr[lane+64], xc = xr[lane+128];
        float s  = xa.x+xa.y+xa.z+xa.w + xb.x+xb.y+xb.z+xb.w + xc.x+xc.y+xc.z+xc.w;
        float ss = xa.x*xa.x+xa.y*xa.y+xa.z*xa.z+xa.w*xa.w
                 + xb.x*xb.x+xb.y*xb.y+xb.z*xb.z+xb.w*xb.w
                 + xc.x*xc.x+xc.y*xc.y+xc.z*xc.z+xc.w*xc.w;
        #pragma unroll
        for (int off = 32; off; off >>= 1) {
            s  += __shfl_xor(s,  off);
            ss += __shfl_xor(ss, off);
        }
        float mean = s * (1.0f/768.0f);
        float inv  = rsqrtf(ss * (1.0f/768.0f) - mean*mean + 1e-6f);
        float m = 0.f;
        m = fmaxf(m, fabsf((xa.x-mean)*inv*ga.x + ba.x));
        m = fmaxf(m, fabsf((xa.y-mean)*inv*ga.y + ba.y));
        m = fmaxf(m, fabsf((xa.z-mean)*inv*ga.z + ba.z));
        m = fmaxf(m, fabsf((xa.w-mean)*inv*ga.w + ba.w));
        m = fmaxf(m, fabsf((xb.x-mean)*inv*gb.x + bb.x));
        m = fmaxf(m, fabsf((xb.y-mean)*inv*gb.y + bb.y));
        m = fmaxf(m, fabsf((xb.z-mean)*inv*gb.z + bb.z));
        m = fmaxf(m, fabsf((xb.w-mean)*inv*gb.w + bb.w));
        m = fmaxf(m, fabsf((xc.x-mean)*inv*gc.x + bc.x));
        m = fmaxf(m, fabsf((xc.y-mean)*inv*gc.y + bc.y));
        m = fmaxf(m, fabsf((xc.z-mean)*inv*gc.z + bc.z));
        m = fmaxf(m, fabsf((xc.w-mean)*inv*gc.w + bc.w));
        wmax = fmaxf(wmax, m);
    }
    #pragma unroll
    for (int off = 32; off; off >>= 1)
        wmax = fmaxf(wmax, __shfl_xor(wmax, off));
    __shared__ float red[4];
    if (lane == 0) red[wv] = wmax;
    __syncthreads();
    if (threadIdx.x == 0) {
        float m = fmaxf(fmaxf(red[0], red[1]), fmaxf(red[2], red[3]));
        atomicMax(slot, __float_as_uint(m));
    }
}

// ---------------- LayerNorm pass 2: wave-per-row, emit packed int8 ----------------
__global__ __launch_bounds__(256) void ln_quant(
    const float* __restrict__ x, const float* __restrict__ g, const float* __restrict__ bia,
    int nrows, char* __restrict__ yq, const unsigned int* __restrict__ slot)
{
    const int lane = threadIdx.x & 63;
    const int wv   = threadIdx.x >> 6;
    int wid = blockIdx.x*4 + wv;
    int nw  = gridDim.x*4;
    const float4* g4 = reinterpret_cast<const float4*>(g);
    const float4* b4 = reinterpret_cast<const float4*>(bia);
    float4 ga = g4[lane], gb = g4[lane+64], gc = g4[lane+128];
    float4 ba = b4[lane], bb = b4[lane+64], bc = b4[lane+128];
    float s1 = __uint_as_float(*slot) / QMAX + 1e-8f;
    float r1 = 1.0f / s1;
    for (int row = wid; row < nrows; row += nw) {
        const float4* xr = reinterpret_cast<const float4*>(x + (size_t)row*768);
        float4 xa = xr[lane], xb = xr[lane+64], xc = xr[lane+128];
        float s  = xa.x+xa.y+xa.z+xa.w + xb.x+xb.y+xb.z+xb.w + xc.x+xc.y+xc.z+xc.w;
        float ss = xa.x*xa.x+xa.y*xa.y+xa.z*xa.z+xa.w*xa.w
                 + xb.x*xb.x+xb.y*xb.y+xb.z*xb.z+xb.w*xb.w
                 + xc.x*xc.x+xc.y*xc.y+xc.z*xc.z+xc.w*xc.w;
        #pragma unroll
        for (int off = 32; off; off >>= 1) {
            s  += __shfl_xor(s,  off);
            ss += __shfl_xor(ss, off);
        }
        float mean = s * (1.0f/768.0f);
        float inv  = rsqrtf(ss * (1.0f/768.0f) - mean*mean + 1e-6f);
        int* yr = reinterpret_cast<int*>(yq + (size_t)row*768);
        float y0, y1, y2, y3;
        int p;
        y0 = (xa.x-mean)*inv*ga.x + ba.x; y1 = (xa.y-mean)*inv*ga.y + ba.y;
        y2 = (xa.z-mean)*inv*ga.z + ba.z; y3 = (xa.w-mean)*inv*ga.w + ba.w;
        p  = ((int)fminf(fmaxf(rintf(y0*r1), -QMAX), QMAX) & 0xff)
           | (((int)fminf(fmaxf(rintf(y1*r1), -QMAX), QMAX) & 0xff) << 8)
           | (((int)fminf(fmaxf(rintf(y2*r1), -QMAX), QMAX) & 0xff) << 16)
           | (((int)fminf(fmaxf(rintf(y3*r1), -QMAX), QMAX) & 0xff) << 24);
        yr[lane] = p;
        y0 = (xb.x-mean)*inv*gb.x + bb.x; y1 = (xb.y-mean)*inv*gb.y + bb.y;
        y2 = (xb.z-mean)*inv*gb.z + bb.z; y3 = (xb.w-mean)*inv*gb.w + bb.w;
        p  = ((int)fminf(fmaxf(rintf(y0*r1), -QMAX), QMAX) & 0xff)
           | (((int)fminf(fmaxf(rintf(y1*r1), -QMAX), QMAX) & 0xff) << 8)
           | (((int)fminf(fmaxf(rintf(y2*r1), -QMAX), QMAX) & 0xff) << 16)
           | (((int)fminf(fmaxf(rintf(y3*r1), -QMAX), QMAX) & 0xff) << 24);
        yr[lane+64] = p;
        y0 = (xc.x-mean)*inv*gc.x + bc.x; y1 = (xc.y-mean)*inv*gc.y + bc.y;
        y2 = (xc.z-mean)*inv*gc.z + bc.z; y3 = (xc.w-mean)*inv*gc.w + bc.w;
        p  = ((int)fminf(fmaxf(rintf(y0*r1), -QMAX), QMAX) & 0xff)
           | (((int)fminf(fmaxf(rintf(y1*r1), -QMAX), QMAX) & 0xff) << 8)
           | (((int)fminf(fmaxf(rintf(y2*r1), -QMAX), QMAX) & 0xff) << 16)
           | (((int)fminf(fmaxf(rintf(y3*r1), -QMAX), QMAX) & 0xff) << 24);
        yr[lane+128] = p;
    }
}

// ---------------- int8 MFMA GEMM: BM=64 ring-3 + hoisted affine pointers + T5 ----------------
// R24 counters: VALUBusy 59% vs MfmaUtil 13.7% — staging addresses were being
// re-derived (64-bit mul + clamp) inside every STAGE. All gload sources are
// affine in the stage index (stride 64B): precompute 3 per-lane base pointers
// once, advance by 64 per call. Same ops, same order -> bit-identical.
// s_setprio(1) around MFMA: 4 independent blocks/CU = role diversity (T5 prereq).
__global__ __launch_bounds__(256) void gemm_i8(
    const char* __restrict__ Alo, const char* __restrict__ Ahi, int split_row,
    const char* __restrict__ Wq,
    const float* __restrict__ bias, const float* __restrict__ residual,
    void* __restrict__ outp, int M, int N, int K,
    const unsigned int* __restrict__ slotA, float epsA,
    const unsigned int* __restrict__ slotW,
    int apply_gelu, int out_bf16, unsigned int* __restrict__ am_slot)
{
    __shared__ __align__(16) char As0[64*64];
    __shared__ __align__(16) char Ws0[128*64];
    __shared__ __align__(16) char As1[64*64];
    __shared__ __align__(16) char Ws1[128*64];
    __shared__ __align__(16) char As2[64*64];
    __shared__ __align__(16) char Ws2[128*64];
    __shared__ float sred[256];

    float sA  = __uint_as_float(*slotA) / QMAX + epsA;
    float sW  = __uint_as_float(*slotW) / QMAX + 1e-8f;

    const int t    = threadIdx.x;
    const int lane = t & 63;
    const int w    = t >> 6;        // wave 0..3: owns cols w*32..+32
    const int lr   = lane & 15;
    const int lk   = lane >> 4;

    const int gx   = gridDim.x;
    const int nwg  = gx * gridDim.y;
    const int wg   = xcd_swizzle(blockIdx.y * gx + blockIdx.x, nwg);
    const int n0   = (wg % gx) * 128;
    const int m0   = (wg / gx) * 64;

    const int rsub = lane >> 2;                          // row within call 0..15
    const int csub = ((lane & 3) ^ ((lane >> 3) & 3)) * 16;  // pre-swizzled src chunk
    const int rchk = (lk ^ ((lr >> 1) & 3)) * 16;        // swizzled read chunk

    // ---- hoisted per-lane source pointers (affine in stage index, stride 64) ----
    int growA = m0 + w*16 + rsub;
    if (growA > M-1) growA = M-1;        // clamp (junk only feeds m>=M, skipped)
    const char* aSrc  = ((growA < split_row) ? Alo : Ahi) + (size_t)growA*K + csub;
    const char* wSrc0 = Wq + (size_t)(n0 + w*32      + rsub)*K + csub;
    const char* wSrc1 = Wq + (size_t)(n0 + w*32 + 16 + rsub)*K + csub;

    int32x4 acc[4][2];
    #pragma unroll
    for (int i = 0; i < 4; ++i)
        #pragma unroll
        for (int j = 0; j < 2; ++j)
            acc[i][j] = (int32x4){0,0,0,0};

    auto STAGE = [&](char* Ab, char* Wb) {   // exactly 3 VMEM ops per wave
        gload16(aSrc,  Ab + (size_t)(w*16)*64);            aSrc  += 64;
        gload16(wSrc0, Wb + (size_t)(w*32)*64);            wSrc0 += 64;
        gload16(wSrc1, Wb + (size_t)(w*32 + 16)*64);       wSrc1 += 64;
    };
    auto COMPUTE = [&](const char* Ab, const char* Wb) {
        int32x4 af[4], bw[2];
        #pragma unroll
        for (int mi = 0; mi < 4; ++mi)
            af[mi] = *reinterpret_cast<const int32x4*>(
                &Ab[(mi*16 + lr)*64 + rchk]);
        #pragma unroll
        for (int ni = 0; ni < 2; ++ni)
            bw[ni] = *reinterpret_cast<const int32x4*>(
                &Wb[(w*32 + ni*16 + lr)*64 + rchk]);
        __builtin_amdgcn_s_setprio(1);
        #pragma unroll
        for (int mi = 0; mi < 4; ++mi)
            #pragma unroll
            for (int ni = 0; ni < 2; ++ni)
                acc[mi][ni] = __builtin_amdgcn_mfma_i32_16x16x64_i8(
                    af[mi], bw[ni], acc[mi][ni], 0, 0, 0);
        __builtin_amdgcn_s_setprio(0);
    };

    const int nk = K >> 6;   // 12 or 48: divisible by 3
    STAGE(As0, Ws0);
    STAGE(As1, Ws1);
    int kt = 0;
    for (; kt + 3 < nk; kt += 3) {
        asm volatile("s_waitcnt vmcnt(3)" ::: "memory");   // buf0 landed (buf1 in flight)
        __builtin_amdgcn_sched_barrier(0);
        __builtin_amdgcn_s_barrier();
        STAGE(As2, Ws2);
        COMPUTE(As0, Ws0);
        asm volatile("s_waitcnt vmcnt(3)" ::: "memory");   // buf1 landed
        __builtin_amdgcn_sched_barrier(0);
        __builtin_amdgcn_s_barrier();
        STAGE(As0, Ws0);
        COMPUTE(As1, Ws1);
        asm volatile("s_waitcnt vmcnt(3)" ::: "memory");   // buf2 landed
        __builtin_amdgcn_sched_barrier(0);
        __builtin_amdgcn_s_barrier();
        STAGE(As1, Ws1);
        COMPUTE(As2, Ws2);
    }
    // final triple (kt == nk-3)
    asm volatile("s_waitcnt vmcnt(3)" ::: "memory");
    __builtin_amdgcn_sched_barrier(0);
    __builtin_amdgcn_s_barrier();
    STAGE(As2, Ws2);
    COMPUTE(As0, Ws0);
    asm volatile("s_waitcnt vmcnt(3)" ::: "memory");       // buf1 landed, buf2 in flight
    __builtin_amdgcn_sched_barrier(0);
    __builtin_amdgcn_s_barrier();
    COMPUTE(As1, Ws1);
    asm volatile("s_waitcnt vmcnt(0)" ::: "memory");       // drain buf2
    __builtin_amdgcn_sched_barrier(0);
    __builtin_amdgcn_s_barrier();
    COMPUTE(As2, Ws2);

    // ---- epilogue: C/D map col=lane&15, row=(lane>>4)*4+reg ----
    float scale = sA * sW;
    float lmax = 0.f;
    #pragma unroll
    for (int mi = 0; mi < 4; ++mi) {
        #pragma unroll
        for (int j = 0; j < 4; ++j) {
            int m = m0 + mi*16 + lk*4 + j;
            if (m >= M) continue;
            #pragma unroll
            for (int ni = 0; ni < 2; ++ni) {
                int n = n0 + w*32 + ni*16 + lr;
                float v = scale * (float)acc[mi][ni][j] + bias[n];
                if (residual) v += residual[(size_t)m*N + n];
                if (apply_gelu) v = gelu_fast(v);
                if (out_bf16) {
                    unsigned short ub = f2bf(v);
                    ((unsigned short*)outp)[(size_t)m*N + n] = ub;
                    lmax = fmaxf(lmax, fabsf(bf2f(ub)));
                } else {
                    ((float*)outp)[(size_t)m*N + n] = v;
                    lmax = fmaxf(lmax, fabsf(v));
                }
            }
        }
    }
    if (am_slot) {
        sred[t] = lmax; __syncthreads();
        for (int o = 128; o; o >>= 1) {
            if (t < o) sred[t] = fmaxf(sred[t], sred[t+o]);
            __syncthreads();
        }
        if (t == 0) atomicMax(am_slot, __float_as_uint(sred[0]));
    }
}

// ---------------- MFMA flash attention: swapped QK^T (unchanged from R15) ----------------
__global__ __launch_bounds__(512) void attn_mfma(
    const unsigned short* __restrict__ qkv, unsigned short* __restrict__ xa,
    unsigned int* __restrict__ am_slot)
{
    const int Nn = 577;
    const float SCL2 = 0.125f * 1.44269504088896340736f;
    const int gx = gridDim.x;
    const int wg = xcd_swizzle(blockIdx.y * gx + blockIdx.x, gx * gridDim.y);
    const int q0 = (wg % gx) * 128;
    const int bh = wg / gx;
    const int h  = bh % 12;
    const int b  = bh / 12;
    const int t  = threadIdx.x;
    const int w    = t >> 6;
    const int lane = t & 63;
    const int lr   = lane & 15;
    const int lk   = lane >> 4;

    __shared__ __align__(16) unsigned short Ks[64][72];
    __shared__ __align__(16) unsigned short Vt[64][72];
    __shared__ __align__(16) unsigned short Pw[8][16][72];
    __shared__ float red8[8];

    const size_t rowstride = 2304;
    const size_t basebh = ((size_t)b * Nn) * rowstride + (size_t)h * 64;

    bf16x8 qf[2];
    {
        int row = q0 + w*16 + lr;
        if (row < Nn) {
            const unsigned short* qrow = qkv + (size_t)row * rowstride + basebh;
            qf[0] = *reinterpret_cast<const bf16x8*>(qrow + lk*8);
            qf[1] = *reinterpret_cast<const bf16x8*>(qrow + 32 + lk*8);
        } else {
            #pragma unroll
            for (int j = 0; j < 8; ++j) { qf[0][j] = 0; qf[1][j] = 0; }
        }
    }

    float m_run = -INFINITY, l_run = 0.f;
    f32x4 acc_o[4];
    #pragma unroll
    for (int df = 0; df < 4; ++df) acc_o[df] = (f32x4){0.f,0.f,0.f,0.f};

    for (int kt = 0; kt < 10; ++kt) {
        __syncthreads();
        {
            int r   = t >> 3;
            int e8  = (t & 7) * 8;
            int key = kt*64 + r;
            ushortx8 ku, vu;
            if (key < Nn) {
                const unsigned short* krow = qkv + (size_t)key * rowstride + basebh;
                ku = *reinterpret_cast<const ushortx8*>(krow + 768  + e8);
                vu = *reinterpret_cast<const ushortx8*>(krow + 1536 + e8);
            } else {
                #pragma unroll
                for (int j = 0; j < 8; ++j) { ku[j] = 0; vu[j] = 0; }
            }
            *reinterpret_cast<ushortx8*>(&Ks[r][e8]) = ku;
            int colp = ((((r >> 3) ^ (t & 7)) << 3) | (r & 7));
            #pragma unroll
            for (int j = 0; j < 8; ++j) Vt[e8 + j][colp] = vu[j];
        }
        __syncthreads();

        f32x4 st[4];
        #pragma unroll
        for (int kf = 0; kf < 4; ++kf) st[kf] = (f32x4){0.f,0.f,0.f,0.f};
        __builtin_amdgcn_s_setprio(1);
        #pragma unroll
        for (int kk = 0; kk < 2; ++kk) {
            #pragma unroll
            for (int kf = 0; kf < 4; ++kf) {
                bf16x8 kfrag = *reinterpret_cast<const bf16x8*>(
                    &Ks[kf*16 + lr][kk*32 + lk*8]);
                st[kf] = __builtin_amdgcn_mfma_f32_16x16x32_bf16(
                    kfrag, qf[kk], st[kf], 0, 0, 0);
            }
        }
        __builtin_amdgcn_s_setprio(0);
        #pragma unroll
        for (int kf = 0; kf < 4; ++kf)
            #pragma unroll
            for (int j = 0; j < 4; ++j) {
                int key = kt*64 + kf*16 + lk*4 + j;
                st[kf][j] = (key < Nn) ? st[kf][j] * SCL2 : -INFINITY;
            }

        float tm = st[0][0];
        #pragma unroll
        for (int kf = 0; kf < 4; ++kf)
            #pragma unroll
            for (int j = 0; j < 4; ++j)
                tm = fmaxf(tm, st[kf][j]);
        tm = fmaxf(tm, __shfl_xor(tm, 16));
        tm = fmaxf(tm, __shfl_xor(tm, 32));

        if (__any(tm > m_run + 8.0f)) {
            float nm  = fmaxf(m_run, tm);
            float fac = exp2f(m_run - nm);
            m_run = nm;
            l_run *= fac;
            float facR[4];
            #pragma unroll
            for (int j = 0; j < 4; ++j)
                facR[j] = __shfl(fac, lk*4 + j);
            #pragma unroll
            for (int df = 0; df < 4; ++df)
                #pragma unroll
                for (int j = 0; j < 4; ++j)
                    acc_o[df][j] *= facR[j];
        }

        float ps = 0.f;
        #pragma unroll
        for (int kf = 0; kf < 4; ++kf)
            #pragma unroll
            for (int j = 0; j < 4; ++j) {
                float p = exp2f(st[kf][j] - m_run);
                st[kf][j] = p;
                ps += p;
            }
        ps += __shfl_xor(ps, 16);
        ps += __shfl_xor(ps, 32);
        l_run += ps;

        #pragma unroll
        for (int kf = 0; kf < 4; ++kf)
            #pragma unroll
            for (int j = 0; j < 4; ++j)
                Pw[w][lr][kf*16 + lk*4 + j] = f2bf(st[kf][j]);

        __builtin_amdgcn_s_setprio(1);
        #pragma unroll
        for (int kk = 0; kk < 2; ++kk) {
            bf16x8 pf = *reinterpret_cast<const bf16x8*>(
                &Pw[w][lr][kk*32 + lk*8]);
            #pragma unroll
            for (int df = 0; df < 4; ++df) {
                int ar = df*2 + (lr >> 3);
                bf16x8 vf = *reinterpret_cast<const bf16x8*>(
                    &Vt[df*16 + lr][(((kk*4 + lk) ^ ar) << 3)]);
                acc_o[df] = __builtin_amdgcn_mfma_f32_16x16x32_bf16(
                    pf, vf, acc_o[df], 0, 0, 0);
            }
        }
        __builtin_amdgcn_s_setprio(0);
    }

    float lrow[4];
    #pragma unroll
    for (int j = 0; j < 4; ++j)
        lrow[j] = __shfl(l_run, lk*4 + j);
    float lmax = 0.f;
    #pragma unroll
    for (int j = 0; j < 4; ++j) {
        int m = q0 + w*16 + lk*4 + j;
        if (m < Nn) {
            float rl = 1.0f / lrow[j];
            #pragma unroll
            for (int df = 0; df < 4; ++df) {
                int d = df*16 + lr;
                float o = acc_o[df][j] * rl;
                unsigned short ob = f2bf(o);
                xa[((size_t)(b*Nn + m))*768 + h*64 + d] = ob;
                lmax = fmaxf(lmax, fabsf(bf2f(ob)));
            }
        }
    }
    #pragma unroll
    for (int off = 1; off < 64; off <<= 1)
        lmax = fmaxf(lmax, __shfl_xor(lmax, off));
    if (lane == 0) red8[w] = lmax;
    __syncthreads();
    if (t == 0) {
        float m = 0.f;
        #pragma unroll
        for (int i = 0; i < 8; ++i) m = fmaxf(m, red8[i]);
        atomicMax(am_slot, __float_as_uint(m));
    }
}

extern "C" void kernel_launch(void* const* d_in, const int* in_sizes, int n_in,
                              void* d_out, int out_size, void* d_ws, size_t ws_size,
                              hipStream_t stream)
{
    const float* x      = (const float*)d_in[0];
    const float* ln1_g  = (const float*)d_in[1];
    const float* ln1_b  = (const float*)d_in[2];
    const float* qkv_w  = (const float*)d_in[3];
    const float* qkv_b  = (const float*)d_in[4];
    const float* proj_w = (const float*)d_in[5];
    const float* proj_b = (const float*)d_in[6];
    const float* ln2_g  = (const float*)d_in[7];
    const float* ln2_b  = (const float*)d_in[8];
    const float* fc1_w  = (const float*)d_in[9];
    const float* fc1_b  = (const float*)d_in[10];
    const float* fc2_w  = (const float*)d_in[11];
    const float* fc2_b  = (const float*)d_in[12];
    float* out = (float*)d_out;

    const int B = 32, Nn = 577, C = 768, H3 = 3072;
    const int M = B * Nn;                    // 18464
    const size_t nA = (size_t)M * C;         // 14,180,352
    const size_t nQ = (size_t)M * 3 * C;
    const size_t nH = (size_t)M * H3;        // 56,721,408

    const size_t NEEDED = 256 + 2359296 + nA + 2*nH;
    if (ws_size < NEEDED) return;

    char* wsb = (char*)d_ws;
    unsigned int* am = (unsigned int*)wsb;
    char* WQ  = wsb + 256;
    char* XNQ = WQ + 2359296;                 // int8 slot (ln out / xaq / hq-side)
    char* BIG = XNQ + nA;
    unsigned short* QKV = (unsigned short*)BIG;
    unsigned short* XA  = (unsigned short*)(BIG + 2*nQ);
    unsigned short* Hbf = (unsigned short*)BIG;
    char* HQ = BIG;                           // in-place int8 h (rows >= SPLIT)

    const int SPLIT = 4608;
    const size_t rowsB = 9216 - 4608, rowsC = 18432 - 9216, rowsD = 18464 - 18432;

    dim3 blk(256);
    int mt64 = (M + 63) / 64;    // 289

    init_slots<<<dim3(1), dim3(16), 0, stream>>>(am);

    // all 4 weight absmaxes in ONE launch (independent of everything else)
    absmax4_f32<<<dim3(512, 4), blk, 0, stream>>>(
        qkv_w, (size_t)3*C*C, proj_w, (size_t)C*C,
        fc1_w, (size_t)H3*C,  fc2_w, (size_t)C*H3, am + 6);

    // ---- attention branch ----
    ln_absmax<<<dim3(2048), blk, 0, stream>>>(x, ln1_g, ln1_b, M, am + 0);
    ln_quant <<<dim3(2048), blk, 0, stream>>>(x, ln1_g, ln1_b, M, XNQ, am + 0);

    quant_w<<<dim3(1024), blk, 0, stream>>>(qkv_w, WQ, (size_t)3*C*C, am + 6);
    gemm_i8<<<dim3(3*C/128, mt64), blk, 0, stream>>>(
        XNQ, XNQ, 0, WQ, qkv_b, nullptr, QKV, M, 3*C, C,
        am + 0, 2e-8f, am + 6, 0, 1, nullptr);

    attn_mfma<<<dim3(5, 384), dim3(512), 0, stream>>>(QKV, XA, am + 2);

    quant_bf2i8<<<dim3(2048), blk, 0, stream>>>(XA, XNQ, nA/8, am + 2);

    quant_w<<<dim3(1024), blk, 0, stream>>>(proj_w, WQ, (size_t)C*C, am + 7);
    gemm_i8<<<dim3(C/128, mt64), blk, 0, stream>>>(
        XNQ, XNQ, 0, WQ, proj_b, x, out, M, C, C,
        am + 2, 1e-8f, am + 7, 0, 0, nullptr);          // out = x + proj

    // ---- mlp branch ----
    ln_absmax<<<dim3(2048), blk, 0, stream>>>(out, ln2_g, ln2_b, M, am + 4);
    ln_quant <<<dim3(2048), blk, 0, stream>>>(out, ln2_g, ln2_b, M, XNQ, am + 4);

    quant_w<<<dim3(1024), blk, 0, stream>>>(fc1_w, WQ, (size_t)H3*C, am + 8);
    gemm_i8<<<dim3(H3/128, mt64), blk, 0, stream>>>(
        XNQ, XNQ, 0, WQ, fc1_b, nullptr, Hbf, M, H3, C,
        am + 4, 2e-8f, am + 8, 1, 1, am + 3);           // gelu, bf16 h, absmax(h)

    quant_bf2i8<<<dim3(2048), blk, 0, stream>>>(
        Hbf, XNQ, (size_t)SPLIT*H3/8, am + 3);
    quant_bf2i8<<<dim3(2048), blk, 0, stream>>>(
        Hbf + (size_t)4608*H3, HQ + (size_t)4608*H3, rowsB*H3/8, am + 3);
    quant_bf2i8<<<dim3(2048), blk, 0, stream>>>(
        Hbf + (size_t)9216*H3, HQ + (size_t)9216*H3, rowsC*H3/8, am + 3);
    quant_bf2i8<<<dim3(48),  blk, 0, stream>>>(
        Hbf + (size_t)18432*H3, HQ + (size_t)18432*H3, rowsD*H3/8, am + 3);

    quant_w<<<dim3(1024), blk, 0, stream>>>(fc2_w, WQ, (size_t)C*H3, am + 9);
    gemm_i8<<<dim3(C/128, mt64), blk, 0, stream>>>(
        XNQ, HQ, SPLIT, WQ, fc2_b, out, out, M, C, H3,
        am + 3, 1e-8f, am + 9, 0, 0, nullptr);          // out += fc2
}